// Round 3
// baseline (184.998 us; speedup 1.0000x reference)
//
#include <hip/hip_runtime.h>
#include <math.h>

// Problem constants
// B=2, H=128, W=256, MD=34, LD=32, NH=4, HD=8, SH=64, K=25, P=7, R=3,
// FF1=512, FF2=256

typedef __attribute__((ext_vector_type(8))) short bfrag;    // 8 bf16 = 4 VGPR
typedef __attribute__((ext_vector_type(4))) float ffrag;    // 4 f32 acc
typedef __attribute__((ext_vector_type(4))) short short4v;  // 8B

union bfi4 { int4 i; bfrag b; };

// Fast tanh-form GELU (~7 VALU ops, |err| vs erf-GELU ~3e-3)
__device__ __forceinline__ float gelu_f(float v) {
  const float z = v * (2.3022077484f + 0.1029451564f * v * v);  // log2e folded
  const float e = __builtin_amdgcn_exp2f(-z);
  return v * __builtin_amdgcn_rcpf(1.0f + e);
}

// exact RNE (cold paths: weight prep)
__device__ __forceinline__ short f2bf(float f) {
  union { float f; unsigned u; } v; v.f = f;
  unsigned r = (v.u + 0x7fffu + ((v.u >> 16) & 1u)) >> 16;
  return (short)r;
}

// round-half-up (2 VALU ops)
__device__ __forceinline__ short f2bf_fast(float f) {
  union { float f; unsigned u; } v; v.f = f;
  return (short)((v.u + 0x8000u) >> 16);
}

__device__ __forceinline__ float bf2f(short s) {
  union { float f; unsigned u; } v;
  v.u = ((unsigned)(unsigned short)s) << 16;
  return v.f;
}

// DPP cross-lane add; butterfly reduction over 16 lanes (all lanes get sum).
template <int CTRL>
__device__ __forceinline__ float dpp_add(float v) {
  union { float f; int i; } s, t;
  s.f = v;
  t.i = __builtin_amdgcn_update_dpp(0, s.i, CTRL, 0xf, 0xf, true);
  return v + t.f;
}
__device__ __forceinline__ float reduce16(float v) {
  v = dpp_add<0xB1>(v);    // quad_perm [1,0,3,2]  = xor1
  v = dpp_add<0x4E>(v);    // quad_perm [2,3,0,1]  = xor2
  v = dpp_add<0x141>(v);   // row_half_mirror      ~ xor4 after fold
  v = dpp_add<0x140>(v);   // row_mirror           ~ xor8 after fold
  return v;
}

// staged bf16 short4 store helper
__device__ __forceinline__ void st4bf(short* p, float4 v) {
  short4v s;
  s[0] = f2bf(v.x); s[1] = f2bf(v.y); s[2] = f2bf(v.z); s[3] = f2bf(v.w);
  *(short4v*)p = s;
}

// ---------------------------------------------------------------------------
// K01: weight prep.
// bid 0..511 : fused conv+MLP1 filters, one block per (h, head n).
//   tileL[f][p]  = sum_k dw[f,k]*psi[k,h,p]      (f32, recomputed per block)
//   tile2[o][p]  = sum_f hw1[n,f,o]*tileL[f][p]  (bf16)
//   Emitted as B-frags [par][kt][nt] = 4096 shorts at wcb[h*16384 + n*4096].
// bid 512..527: fw2 kt-tile transposes. 528..529: fw1 halves. 530: fw3.
// 531: hb1e.  Max LDS 24832 B -> 6 blocks/CU.
// ---------------------------------------------------------------------------
__global__ __launch_bounds__(256) void k01_prep(
    const float* __restrict__ psi, const float* __restrict__ dw,
    const float* __restrict__ db,
    const float* __restrict__ fw1, const float* __restrict__ fw2,
    const float* __restrict__ fw3, const float* __restrict__ hw1,
    const float* __restrict__ hb1,
    short* __restrict__ wcb, short* __restrict__ fw1s,
    short* __restrict__ fw2s, short* __restrict__ fw3s,
    float* __restrict__ hb1e) {
  __shared__ __align__(16) char sm[24832];
  const int bid = blockIdx.x;
  const int tid = threadIdx.x;

  if (bid < 512) {            // ---- fused conv+MLP1 fragments per (h, n)
    float* tileL = (float*)sm;               // [64][52] f32   = 13312 B
    float* hw1n  = (float*)(sm + 13312);     // [64][32] f32   =  8192 B
    short* tile2 = (short*)(sm + 21504);     // [32][52] bf16  =  3328 B
    const int h = bid >> 2;
    const int n = bid & 3;
    const int lane = tid & 63;
    const int w = __builtin_amdgcn_readfirstlane(tid >> 6);

    // stage this head's hw1[n] (2048 floats)
    for (int e = tid; e < 512; e += 256)
      ((float4*)hw1n)[e] = ((const float4*)(hw1 + n * 2048))[e];

    float dwreg[25];
#pragma unroll
    for (int kk = 0; kk < 25; ++kk) dwreg[kk] = dw[lane * 25 + kk];
    const int p0 = w * 13;
    const int pend = (p0 + 13 < 49) ? (p0 + 13) : 49;
#pragma unroll 1
    for (int p = p0; p < pend; ++p) {
      float acc = 0.f;
#pragma unroll
      for (int kk = 0; kk < 25; ++kk)
        acc += dwreg[kk] * psi[kk * 6272 + h * 49 + p];   // uniform -> s_load
      tileL[lane * 52 + p] = acc;
    }
    __syncthreads();

    // tile2[o][p2,p2+1] = sum_f hw1n[f][o] * tileL[f][p2,p2+1]
    const int o = tid & 31;
#pragma unroll 1
    for (int pp = tid >> 5; pp < 25; pp += 8) {
      const int p2 = pp * 2;
      float a0 = 0.f, a1 = 0.f;
#pragma unroll 4
      for (int f = 0; f < 64; ++f) {
        const float wv = hw1n[f * 32 + o];
        a0 += wv * tileL[f * 52 + p2];
        a1 += wv * tileL[f * 52 + p2 + 1];
      }
      tile2[o * 52 + p2] = f2bf(a0);
      if (p2 + 1 < 49) tile2[o * 52 + p2 + 1] = f2bf(a1);
    }
    __syncthreads();

    short* outp = wcb + h * 16384 + n * 4096;
    for (int idx = tid; idx < 4096; idx += 256) {
      const int jj = idx & 7, ln = (idx >> 3) & 63;
      const int nt = (idx >> 9) & 1, kt = (idx >> 10) & 1;
      const int par = idx >> 11;
      const int k = kt * 32 + ((ln >> 4) << 3) + jj;
      const int oo = nt * 16 + (ln & 15);
      const int r = k >> 3, dlt = k & 7;
      const int j = par ? (dlt - 1) : dlt;
      short v = 0;
      if (r < 7 && j >= 0 && j < 7) v = tile2[oo * 52 + r * 7 + j];
      outp[idx] = v;
    }
    return;
  }

  if (bid < 528) {            // ---- fw2 kt-tile transpose: K rows 32, N 256
    short* S = (short*)sm;               // [32][260]
    const int kt = bid - 512;
    const float* src = fw2 + kt * 8192;
    for (int q = tid; q < 2048; q += 256) {
      const int lin = q * 4;
      const int kk = lin >> 8, nn = lin & 255;
      st4bf(S + kk * 260 + nn, *(const float4*)(src + lin));
    }
    __syncthreads();
    short* dst = fw2s + kt * 8192;
    for (int q = tid; q < 8192; q += 256) {
      const int jj = q & 7, lane = (q >> 3) & 63, nt = q >> 9;
      const int kk = (lane >> 4) * 8 + jj, nn = nt * 16 + (lane & 15);
      dst[q] = S[kk * 260 + nn];
    }
    return;
  }

  if (bid < 530) {            // ---- fw1 transpose half X: K 32, N 256
    const int X = bid - 528;
    short* S = (short*)sm;               // [32][260]
    for (int q = tid; q < 2048; q += 256) {
      const int lin = q * 4;
      const int kk = lin >> 8, nn = lin & 255;
      st4bf(S + kk * 260 + nn, *(const float4*)(fw1 + kk * 512 + X * 256 + nn));
    }
    __syncthreads();
    for (int q = tid; q < 8192; q += 256) {
      const int jj = q & 7, lane = (q >> 3) & 63, ntl = q >> 9;
      const int kk = (lane >> 4) * 8 + jj, nn = ntl * 16 + (lane & 15);
      fw1s[X * 8192 + q] = S[kk * 260 + nn];
    }
    return;
  }

  if (bid == 530) {           // ---- fw3 transpose: K 256, N 32
    short* S = (short*)sm;               // [256][36]
    for (int q = tid; q < 2048; q += 256) {
      const int lin = q * 4;
      const int kk = lin >> 5, nn = lin & 31;
      st4bf(S + kk * 36 + nn, *(const float4*)(fw3 + lin));
    }
    __syncthreads();
    for (int q = tid; q < 8192; q += 256) {
      const int jj = q & 7, lane = (q >> 3) & 63;
      const int nt = (q >> 9) & 1, kt = q >> 10;
      const int kk = kt * 32 + (lane >> 4) * 8 + jj, nn = nt * 16 + (lane & 15);
      fw3s[q] = S[kk * 36 + nn];
    }
    return;
  }

  // ---- bid 531: hb1e[n][o] = hb1[n][o] + sum_s hw1[n][s][o]*db[s] (exact)
  if (tid < 128) {
    const int n = tid >> 5, o = tid & 31;
    float acc = hb1[n * 32 + o];
#pragma unroll
    for (int s = 0; s < 64; ++s)
      acc += hw1[n * 2048 + s * 32 + o] * db[s];
    hb1e[tid] = acc;
  }
}

// ---------------------------------------------------------------------------
// K23: fused DISCO conv (hw1-folded) + head MLP tail + final MLP.
// grid (8,128,2) = 2048 blocks, block 256.
// LDS diet: 20256 B -> 8 blocks/CU -> the ENTIRE grid (256 CU x 8) is
// resident in one generation: no tail, 32 waves/CU of latency hiding.
// (Round-2 counters: 42% occupancy, 53% VALUBusy at 6 blocks/CU with a
// 6+2 two-generation schedule -> ~2x away from the VALU issue floor.)
// sX repack: row stride 40 shorts (was 48), 7 rows (was 8; virtual row 7
// reads next channel's row 0 -- finite bf16 x zero weights = 0).
//   sX [0,18080) + sM [18080,20256); phase B: sT1h/sT2 [0,16896) alias sX,
//   sO [0,4352) aliases sT2 behind an extra barrier.
// XCD-aware swizzle: 16 consecutive slots share one h -> wcb[h] L2-resident.
// ---------------------------------------------------------------------------
__global__ __launch_bounds__(256, 8) void k23_fused(
    const float* __restrict__ x,    const short* __restrict__ wcb,
    const float* __restrict__ hb1e, const float* __restrict__ hw2,
    const float* __restrict__ hb2,
    const short* __restrict__ fw1s, const short* __restrict__ fw2s,
    const short* __restrict__ fw3s,
    const float* __restrict__ fb1,  const float* __restrict__ fb2,
    const float* __restrict__ fb3,  float* __restrict__ outb) {
  __shared__ __align__(16) char smem[20256];
  short* sX = (short*)smem;                  // [32 ch][280] bf16 (phase A)
  short* sM = (short*)(smem + 18080);        // [32][34]  bf16
  float* sO = (float*)smem;                  // [32][34]  f32 (epilogue only)

  const int tid = threadIdx.x;

  // XCD-aware bijective remap (8 XCDs x 256 slots; 16 slots share one h)
  const int lin  = blockIdx.x + (blockIdx.y << 3) + (blockIdx.z << 10);
  const int xcd  = lin & 7;
  const int slot = lin >> 3;
  const int w0   = (slot & 7) * 32;
  const int b    = (slot >> 3) & 1;
  const int h    = (xcd << 4) | (slot >> 4);

  const int lane = tid & 63, lm = lane & 15, lq = lane >> 4;
  const int n = tid >> 6;  // wave == head in phase A

  // ---- early independent global loads (hide under x staging) ----
  bfrag cW[2][2][2];
#pragma unroll
  for (int par = 0; par < 2; ++par)
#pragma unroll
    for (int kt = 0; kt < 2; ++kt)
#pragma unroll
      for (int nt = 0; nt < 2; ++nt)
        cW[par][kt][nt] = *(const bfrag*)(wcb + h * 16384 + n * 4096 +
                            ((par * 2 + kt) * 2 + nt) * 512 + lane * 8);
  // sincos passthrough values (written at the coalesced epilogue)
  float2 scv;
  if (tid < 32)
    scv = *(const float2*)&x[(size_t)(((b * 128 + h) * 256 + w0 + tid)) * 34 + 32];
  float hb1v[2], hw2v[2];
#pragma unroll
  for (int nt = 0; nt < 2; ++nt) {
    hb1v[nt] = hb1e[n * 32 + nt * 16 + lm];
    hw2v[nt] = hw2[n * 32 + nt * 16 + lm];
  }
  const float hb2n = hb2[n];

  {  // zero-fill whole LDS (tap pads must be 0.0bf16, never garbage)
    int4* p = (int4*)smem;
    int4 z; z.x = z.y = z.z = z.w = 0;
    for (int e = tid; e < 20256 / 16; e += 256) p[e] = z;
  }
  __syncthreads();

  // stage x tile as bf16; r-outer => wp = e>>4 (no integer division)
  // channel stride 280 shorts, row stride 40 shorts
#pragma unroll 1
  for (int r = 0; r < 7; ++r) {
    int hr = h - 3 + r; hr = hr < 0 ? 0 : (hr > 127 ? 127 : hr);
    const float* __restrict__ xrow = x + (size_t)((b * 128 + hr) * 256) * 34;
    short* __restrict__ sxr = sX + r * 40;
    for (int e = tid; e < 39 * 16; e += 256) {
      const int c2 = e & 15;
      const int wp = e >> 4;
      const int wr = (w0 - 3 + wp) & 255;
      const float2 v = *(const float2*)&xrow[wr * 34 + c2 * 2];
      short* dp = sxr + (c2 * 2) * 280 + wp;
      dp[0]   = f2bf_fast(v.x);
      dp[280] = f2bf_fast(v.y);
    }
  }
  __syncthreads();

  const int* tpB = (const int*)sX;

  // ---- phase A main loop: conv MFMA -> MLP1 pre-activations directly
#pragma unroll 1
  for (int i = 0; i < 8; ++i) {
    const int c = n * 8 + i;

    // tap A-frags (shared by both parities): dword-aligned gathers
    // channel stride 140 dwords, row stride 20 dwords; u1 = rows 4..7
    const int base0 = c * 140 + lq * 20 + lm;
    bfi4 u0, u1;
    u0.i.x = tpB[base0];      u0.i.y = tpB[base0 + 1];
    u0.i.z = tpB[base0 + 2];  u0.i.w = tpB[base0 + 3];
    u1.i.x = tpB[base0 + 80]; u1.i.y = tpB[base0 + 81];
    u1.i.z = tpB[base0 + 82]; u1.i.w = tpB[base0 + 83];

#pragma unroll
    for (int par = 0; par < 2; ++par) {
      ffrag h0 = {0.f, 0.f, 0.f, 0.f}, h1 = {0.f, 0.f, 0.f, 0.f};
      h0 = __builtin_amdgcn_mfma_f32_16x16x32_bf16(u0.b, cW[par][0][0], h0, 0, 0, 0);
      h0 = __builtin_amdgcn_mfma_f32_16x16x32_bf16(u1.b, cW[par][1][0], h0, 0, 0, 0);
      h1 = __builtin_amdgcn_mfma_f32_16x16x32_bf16(u0.b, cW[par][0][1], h1, 0, 0, 0);
      h1 = __builtin_amdgcn_mfma_f32_16x16x32_bf16(u1.b, cW[par][1][1], h1, 0, 0, 0);

      // h0/h1: row = pixel m = lq*4+rr, col o = {lm, 16+lm}
#pragma unroll
      for (int rr = 0; rr < 4; ++rr) {
        float v = gelu_f(h0[rr] + hb1v[0]) * hw2v[0] +
                  gelu_f(h1[rr] + hb1v[1]) * hw2v[1];
        v = reduce16(v);
        const int p = 2 * (lq * 4 + rr) + par;
        const float res = bf2f(sX[c * 280 + 123 + p]);  // x center tap (row 3)
        if (lm == 0) sM[p * 34 + c] = f2bf_fast(v + hb2n + res);
      }
    }
  }
  __syncthreads();

  // ---- phase B: fused MLP 32->512(gelu)->256(gelu)->32 (+residual),
  // split-K: t1 in two 256-col halves. sT2 aliases sT1h (barrier-separated).
  short* sT1h = (short*)smem;
  short* sT2  = (short*)smem;
  const int wave = n;
  const int koff = lq * 8;
  const int mt3 = wave & 1;
  const int nt3 = wave >> 1;
  const int col3 = nt3 * 16 + lm;
  const int pixg = (b * 128 + h) * 256 + w0;

  bfrag aF[2];
#pragma unroll
  for (int mt = 0; mt < 2; ++mt)
    aF[mt] = *(const bfrag*)(sM + (mt * 16 + lm) * 34 + koff);
  float res3[4];
#pragma unroll
  for (int r = 0; r < 4; ++r)
    res3[r] = bf2f(sM[(mt3 * 16 + lq * 4 + r) * 34 + col3]);

  const int n0 = wave * 4;
  ffrag acc[2][4];
#pragma unroll
  for (int mt = 0; mt < 2; ++mt)
#pragma unroll
    for (int ni = 0; ni < 4; ++ni) acc[mt][ni] = ffrag{0.f, 0.f, 0.f, 0.f};
  const short* w2base = fw2s + n0 * 512 + lane * 8;

#pragma unroll 1
  for (int H = 0; H < 2; ++H) {
    // layer 1, half H: waves produce cols [H*256, H*256+256)
    bfrag b1f[4];
#pragma unroll
    for (int ni = 0; ni < 4; ++ni)
      b1f[ni] = *(const bfrag*)(fw1s + (H * 16 + wave * 4 + ni) * 512 + lane * 8);
#pragma unroll
    for (int ni = 0; ni < 4; ++ni) {
      const int ntl = wave * 4 + ni;          // within-half tile
#pragma unroll
      for (int mt = 0; mt < 2; ++mt) {
        ffrag cc = {0.f, 0.f, 0.f, 0.f};
        cc = __builtin_amdgcn_mfma_f32_16x16x32_bf16(aF[mt], b1f[ni], cc, 0, 0, 0);
        const int colg = H * 256 + ntl * 16 + lm;
        const float bias = fb1[colg];
#pragma unroll
        for (int r = 0; r < 4; ++r) {
          const int row = mt * 16 + lq * 4 + r;
          sT1h[row * 264 + ntl * 16 + lm] = f2bf_fast(gelu_f(cc[r] + bias));
        }
      }
    }
    __syncthreads();

    // layer 2 partial accumulation over this half's K=256
#pragma unroll 2
    for (int kt = 0; kt < 8; ++kt) {
      bfrag bv[4];
#pragma unroll
      for (int ni = 0; ni < 4; ++ni)
        bv[ni] = *(const bfrag*)(w2base + (H * 8 + kt) * 8192 + ni * 512);
      const bfrag a0 = *(const bfrag*)(sT1h + lm * 264 + kt * 32 + koff);
      const bfrag a1 = *(const bfrag*)(sT1h + (16 + lm) * 264 + kt * 32 + koff);
#pragma unroll
      for (int ni = 0; ni < 4; ++ni) {
        acc[0][ni] = __builtin_amdgcn_mfma_f32_16x16x32_bf16(a0, bv[ni], acc[0][ni], 0, 0, 0);
        acc[1][ni] = __builtin_amdgcn_mfma_f32_16x16x32_bf16(a1, bv[ni], acc[1][ni], 0, 0, 0);
      }
    }
    __syncthreads();   // before next half overwrites sT1h
  }

  // t2 epilogue (sT2 == sT1h region; all layer-2 reads drained by barrier)
#pragma unroll
  for (int mt = 0; mt < 2; ++mt)
#pragma unroll
    for (int ni = 0; ni < 4; ++ni) {
      const int col = (n0 + ni) * 16 + lm;
      const float bias = fb2[col];
#pragma unroll
      for (int r = 0; r < 4; ++r) {
        const int row = mt * 16 + lq * 4 + r;
        sT2[row * 264 + col] = f2bf_fast(gelu_f(acc[mt][ni][r] + bias));
      }
    }
  __syncthreads();

  // layer 3 (reads sT2), then barrier, then sO aliases sT2 for the burst
  ffrag c3 = {0.f, 0.f, 0.f, 0.f};
  const short* sA3 = sT2 + (mt3 * 16 + lm) * 264 + koff;
#pragma unroll
  for (int kt = 0; kt < 8; ++kt) {
    const bfrag a = *(const bfrag*)(sA3 + kt * 32);
    const bfrag bw = *(const bfrag*)(fw3s + nt3 * 512 + kt * 1024 + lane * 8);
    c3 = __builtin_amdgcn_mfma_f32_16x16x32_bf16(a, bw, c3, 0, 0, 0);
  }
  __syncthreads();   // all sT2 reads done before sO overwrite
  {
    const float bias = fb3[col3];
#pragma unroll
    for (int r = 0; r < 4; ++r) {
      const int row = mt3 * 16 + lq * 4 + r;
      sO[row * 34 + col3] = c3[r] + bias + res3[r];
    }
  }
  if (tid < 32) { sO[tid * 34 + 32] = scv.x; sO[tid * 34 + 33] = scv.y; }
  __syncthreads();
  {
    const float4* sp = (const float4*)sO;           // 1088 floats = 272 f4
    float4* dp = (float4*)(outb + (size_t)pixg * 34);
    for (int e = tid; e < 272; e += 256) dp[e] = sp[e];
  }
}

// ---------------------------------------------------------------------------
extern "C" void kernel_launch(void* const* d_in, const int* in_sizes, int n_in,
                              void* d_out, int out_size, void* d_ws, size_t ws_size,
                              hipStream_t stream) {
  const float* x   = (const float*)d_in[0];
  const float* psi = (const float*)d_in[1];
  const float* dw  = (const float*)d_in[2];
  const float* db  = (const float*)d_in[3];
  const float* hw1 = (const float*)d_in[4];
  const float* hb1 = (const float*)d_in[5];
  const float* hw2 = (const float*)d_in[6];
  const float* hb2 = (const float*)d_in[7];
  const float* fw1 = (const float*)d_in[8];
  const float* fb1 = (const float*)d_in[9];
  const float* fw2 = (const float*)d_in[10];
  const float* fb2 = (const float*)d_in[11];
  const float* fw3 = (const float*)d_in[12];
  const float* fb3 = (const float*)d_in[13];
  float* outb = (float*)d_out;

  // workspace (~4.5 MB)
  short* wcb  = (short*)d_ws;        // 128*16384 = 2097152 shorts
  short* fw1s = wcb + 2097152;       // 16384
  short* fw2s = fw1s + 16384;        // 131072
  short* fw3s = fw2s + 131072;       // 8192
  float* hb1e = (float*)(fw3s + 8192);  // 128 floats

  hipLaunchKernelGGL(k01_prep, dim3(532), dim3(256), 0, stream,
                     psi, dw, db, fw1, fw2, fw3, hw1, hb1,
                     wcb, fw1s, fw2s, fw3s, hb1e);
  hipLaunchKernelGGL(k23_fused, dim3(8, 128, 2), dim3(256), 0, stream,
                     x, wcb, hb1e, hw2, hb2,
                     fw1s, fw2s, fw3s, fb1, fb2, fb3, outb);
}

// Round 4
// 169.072 us; speedup vs baseline: 1.0942x; 1.0942x over previous
//
#include <hip/hip_runtime.h>
#include <math.h>

// Problem constants
// B=2, H=128, W=256, MD=34, LD=32, NH=4, HD=8, SH=64, K=25, P=7, R=3,
// FF1=512, FF2=256

typedef __attribute__((ext_vector_type(8))) short bfrag;    // 8 bf16 = 4 VGPR
typedef __attribute__((ext_vector_type(4))) float ffrag;    // 4 f32 acc
typedef __attribute__((ext_vector_type(4))) short short4v;  // 8B

union bfi4 { int4 i; bfrag b; };

// Fast tanh-form GELU (~7 VALU ops, |err| vs erf-GELU ~3e-3)
__device__ __forceinline__ float gelu_f(float v) {
  const float z = v * (2.3022077484f + 0.1029451564f * v * v);  // log2e folded
  const float e = __builtin_amdgcn_exp2f(-z);
  return v * __builtin_amdgcn_rcpf(1.0f + e);
}

// exact RNE (cold paths: weight prep)
__device__ __forceinline__ short f2bf(float f) {
  union { float f; unsigned u; } v; v.f = f;
  unsigned r = (v.u + 0x7fffu + ((v.u >> 16) & 1u)) >> 16;
  return (short)r;
}

// round-half-up (2 VALU ops)
__device__ __forceinline__ short f2bf_fast(float f) {
  union { float f; unsigned u; } v; v.f = f;
  return (short)((v.u + 0x8000u) >> 16);
}

__device__ __forceinline__ float bf2f(short s) {
  union { float f; unsigned u; } v;
  v.u = ((unsigned)(unsigned short)s) << 16;
  return v.f;
}

// DPP cross-lane add; butterfly reduction over 16 lanes (all lanes get sum).
template <int CTRL>
__device__ __forceinline__ float dpp_add(float v) {
  union { float f; int i; } s, t;
  s.f = v;
  t.i = __builtin_amdgcn_update_dpp(0, s.i, CTRL, 0xf, 0xf, true);
  return v + t.f;
}
__device__ __forceinline__ float reduce16(float v) {
  v = dpp_add<0xB1>(v);    // quad_perm [1,0,3,2]  = xor1
  v = dpp_add<0x4E>(v);    // quad_perm [2,3,0,1]  = xor2
  v = dpp_add<0x141>(v);   // row_half_mirror      ~ xor4 after fold
  v = dpp_add<0x140>(v);   // row_mirror           ~ xor8 after fold
  return v;
}

// staged bf16 short4 store helper
__device__ __forceinline__ void st4bf(short* p, float4 v) {
  short4v s;
  s[0] = f2bf(v.x); s[1] = f2bf(v.y); s[2] = f2bf(v.z); s[3] = f2bf(v.w);
  *(short4v*)p = s;
}

// ---------------------------------------------------------------------------
// K01: weight prep.
// bid 0..511 : fused conv+MLP1 filters, one block per (h, head n).
//   tileL[f][p]  = sum_k dw[f,k]*psi[k,h,p]      (f32, recomputed per block)
//   tile2[o][p]  = sum_f hw1[n,f,o]*tileL[f][p]  (bf16)
//   Emitted as B-frags [par][kt][nt] = 4096 shorts at wcb[h*16384 + n*4096].
// bid 512..527: fw2 kt-tile transposes. 528..529: fw1 halves. 530: fw3.
// 531: hb1e.  Max LDS 24832 B -> 6 blocks/CU.
// ---------------------------------------------------------------------------
__global__ __launch_bounds__(256) void k01_prep(
    const float* __restrict__ psi, const float* __restrict__ dw,
    const float* __restrict__ db,
    const float* __restrict__ fw1, const float* __restrict__ fw2,
    const float* __restrict__ fw3, const float* __restrict__ hw1,
    const float* __restrict__ hb1,
    short* __restrict__ wcb, short* __restrict__ fw1s,
    short* __restrict__ fw2s, short* __restrict__ fw3s,
    float* __restrict__ hb1e) {
  __shared__ __align__(16) char sm[24832];
  const int bid = blockIdx.x;
  const int tid = threadIdx.x;

  if (bid < 512) {            // ---- fused conv+MLP1 fragments per (h, n)
    float* tileL = (float*)sm;               // [64][52] f32   = 13312 B
    float* hw1n  = (float*)(sm + 13312);     // [64][32] f32   =  8192 B
    short* tile2 = (short*)(sm + 21504);     // [32][52] bf16  =  3328 B
    const int h = bid >> 2;
    const int n = bid & 3;
    const int lane = tid & 63;
    const int w = __builtin_amdgcn_readfirstlane(tid >> 6);

    // stage this head's hw1[n] (2048 floats)
    for (int e = tid; e < 512; e += 256)
      ((float4*)hw1n)[e] = ((const float4*)(hw1 + n * 2048))[e];

    float dwreg[25];
#pragma unroll
    for (int kk = 0; kk < 25; ++kk) dwreg[kk] = dw[lane * 25 + kk];
    const int p0 = w * 13;
    const int pend = (p0 + 13 < 49) ? (p0 + 13) : 49;
#pragma unroll 1
    for (int p = p0; p < pend; ++p) {
      float acc = 0.f;
#pragma unroll
      for (int kk = 0; kk < 25; ++kk)
        acc += dwreg[kk] * psi[kk * 6272 + h * 49 + p];   // uniform -> s_load
      tileL[lane * 52 + p] = acc;
    }
    __syncthreads();

    // tile2[o][p2,p2+1] = sum_f hw1n[f][o] * tileL[f][p2,p2+1]
    const int o = tid & 31;
#pragma unroll 1
    for (int pp = tid >> 5; pp < 25; pp += 8) {
      const int p2 = pp * 2;
      float a0 = 0.f, a1 = 0.f;
#pragma unroll 4
      for (int f = 0; f < 64; ++f) {
        const float wv = hw1n[f * 32 + o];
        a0 += wv * tileL[f * 52 + p2];
        a1 += wv * tileL[f * 52 + p2 + 1];
      }
      tile2[o * 52 + p2] = f2bf(a0);
      if (p2 + 1 < 49) tile2[o * 52 + p2 + 1] = f2bf(a1);
    }
    __syncthreads();

    short* outp = wcb + h * 16384 + n * 4096;
    for (int idx = tid; idx < 4096; idx += 256) {
      const int jj = idx & 7, ln = (idx >> 3) & 63;
      const int nt = (idx >> 9) & 1, kt = (idx >> 10) & 1;
      const int par = idx >> 11;
      const int k = kt * 32 + ((ln >> 4) << 3) + jj;
      const int oo = nt * 16 + (ln & 15);
      const int r = k >> 3, dlt = k & 7;
      const int j = par ? (dlt - 1) : dlt;
      short v = 0;
      if (r < 7 && j >= 0 && j < 7) v = tile2[oo * 52 + r * 7 + j];
      outp[idx] = v;
    }
    return;
  }

  if (bid < 528) {            // ---- fw2 kt-tile transpose: K rows 32, N 256
    short* S = (short*)sm;               // [32][260]
    const int kt = bid - 512;
    const float* src = fw2 + kt * 8192;
    for (int q = tid; q < 2048; q += 256) {
      const int lin = q * 4;
      const int kk = lin >> 8, nn = lin & 255;
      st4bf(S + kk * 260 + nn, *(const float4*)(src + lin));
    }
    __syncthreads();
    short* dst = fw2s + kt * 8192;
    for (int q = tid; q < 8192; q += 256) {
      const int jj = q & 7, lane = (q >> 3) & 63, nt = q >> 9;
      const int kk = (lane >> 4) * 8 + jj, nn = nt * 16 + (lane & 15);
      dst[q] = S[kk * 260 + nn];
    }
    return;
  }

  if (bid < 530) {            // ---- fw1 transpose half X: K 32, N 256
    const int X = bid - 528;
    short* S = (short*)sm;               // [32][260]
    for (int q = tid; q < 2048; q += 256) {
      const int lin = q * 4;
      const int kk = lin >> 8, nn = lin & 255;
      st4bf(S + kk * 260 + nn, *(const float4*)(fw1 + kk * 512 + X * 256 + nn));
    }
    __syncthreads();
    for (int q = tid; q < 8192; q += 256) {
      const int jj = q & 7, lane = (q >> 3) & 63, ntl = q >> 9;
      const int kk = (lane >> 4) * 8 + jj, nn = ntl * 16 + (lane & 15);
      fw1s[X * 8192 + q] = S[kk * 260 + nn];
    }
    return;
  }

  if (bid == 530) {           // ---- fw3 transpose: K 256, N 32
    short* S = (short*)sm;               // [256][36]
    for (int q = tid; q < 2048; q += 256) {
      const int lin = q * 4;
      const int kk = lin >> 5, nn = lin & 31;
      st4bf(S + kk * 36 + nn, *(const float4*)(fw3 + lin));
    }
    __syncthreads();
    for (int q = tid; q < 8192; q += 256) {
      const int jj = q & 7, lane = (q >> 3) & 63;
      const int nt = (q >> 9) & 1, kt = q >> 10;
      const int kk = kt * 32 + (lane >> 4) * 8 + jj, nn = nt * 16 + (lane & 15);
      fw3s[q] = S[kk * 36 + nn];
    }
    return;
  }

  // ---- bid 531: hb1e[n][o] = hb1[n][o] + sum_s hw1[n][s][o]*db[s] (exact)
  if (tid < 128) {
    const int n = tid >> 5, o = tid & 31;
    float acc = hb1[n * 32 + o];
#pragma unroll
    for (int s = 0; s < 64; ++s)
      acc += hw1[n * 2048 + s * 32 + o] * db[s];
    hb1e[tid] = acc;
  }
}

// ---------------------------------------------------------------------------
// K23: fused DISCO conv (hw1-folded) + head MLP tail + final MLP.
// grid (8,128,2) = 2048 blocks, block 256, LDS 20256 B.
// __launch_bounds__(256,7): VGPR cap 72 (round-3's cap-64 spilled ~135 MB of
// scratch -- FETCH 61 MB / WRITE 101 MB -- and ate the occupancy gain).
// Register diet to fit 72 spill-free:
//   - phase A par-OUTER: one parity's cW (16 VGPRs) live at a time, loaded
//     from L2-hot wcb per parity pass (tap gathers re-issued per parity).
//   - res3 / sincos passthrough deferred to the epilogue (sM survives B).
//   - aF reloaded per half; b1f loaded per-ni.
// sX [0,18080) + sM [18080,20256); phase B sT1h/sT2 [0,16896) alias sX;
// sO [0,4352) aliases sT2 behind a barrier. XCD-aware swizzle as before.
// ---------------------------------------------------------------------------
__global__ __launch_bounds__(256, 7) void k23_fused(
    const float* __restrict__ x,    const short* __restrict__ wcb,
    const float* __restrict__ hb1e, const float* __restrict__ hw2,
    const float* __restrict__ hb2,
    const short* __restrict__ fw1s, const short* __restrict__ fw2s,
    const short* __restrict__ fw3s,
    const float* __restrict__ fb1,  const float* __restrict__ fb2,
    const float* __restrict__ fb3,  float* __restrict__ outb) {
  __shared__ __align__(16) char smem[20256];
  short* sX = (short*)smem;                  // [32 ch][280] bf16 (phase A)
  short* sM = (short*)(smem + 18080);        // [32][34]  bf16
  float* sO = (float*)smem;                  // [32][34]  f32 (epilogue only)

  const int tid = threadIdx.x;

  // XCD-aware bijective remap (8 XCDs x 256 slots; 16 slots share one h)
  const int lin  = blockIdx.x + (blockIdx.y << 3) + (blockIdx.z << 10);
  const int xcd  = lin & 7;
  const int slot = lin >> 3;
  const int w0   = (slot & 7) * 32;
  const int b    = (slot >> 3) & 1;
  const int h    = (xcd << 4) | (slot >> 4);

  const int lane = tid & 63, lm = lane & 15, lq = lane >> 4;
  const int n = tid >> 6;  // wave == head in phase A

  float hb1v[2], hw2v[2];
#pragma unroll
  for (int nt = 0; nt < 2; ++nt) {
    hb1v[nt] = hb1e[n * 32 + nt * 16 + lm];
    hw2v[nt] = hw2[n * 32 + nt * 16 + lm];
  }
  const float hb2n = hb2[n];

  {  // zero-fill whole LDS (tap pads must be 0.0bf16, never garbage)
    int4* p = (int4*)smem;
    int4 z; z.x = z.y = z.z = z.w = 0;
    for (int e = tid; e < 20256 / 16; e += 256) p[e] = z;
  }
  __syncthreads();

  // stage x tile as bf16; r-outer => wp = e>>4 (no integer division)
  // channel stride 280 shorts, row stride 40 shorts
#pragma unroll 1
  for (int r = 0; r < 7; ++r) {
    int hr = h - 3 + r; hr = hr < 0 ? 0 : (hr > 127 ? 127 : hr);
    const float* __restrict__ xrow = x + (size_t)((b * 128 + hr) * 256) * 34;
    short* __restrict__ sxr = sX + r * 40;
    for (int e = tid; e < 39 * 16; e += 256) {
      const int c2 = e & 15;
      const int wp = e >> 4;
      const int wr = (w0 - 3 + wp) & 255;
      const float2 v = *(const float2*)&xrow[wr * 34 + c2 * 2];
      short* dp = sxr + (c2 * 2) * 280 + wp;
      dp[0]   = f2bf_fast(v.x);
      dp[280] = f2bf_fast(v.y);
    }
  }
  __syncthreads();

  const int* tpB = (const int*)sX;

  // ---- phase A: par-outer (halves live cW regs), conv MFMA -> MLP1 preacts
#pragma unroll 1
  for (int par = 0; par < 2; ++par) {
    bfrag cw[2][2];
#pragma unroll
    for (int kt = 0; kt < 2; ++kt)
#pragma unroll
      for (int nt = 0; nt < 2; ++nt)
        cw[kt][nt] = *(const bfrag*)(wcb + h * 16384 + n * 4096 +
                         ((par * 2 + kt) * 2 + nt) * 512 + lane * 8);

#pragma unroll 1
    for (int i = 0; i < 8; ++i) {
      const int c = n * 8 + i;

      // tap A-frags: dword-aligned gathers
      // channel stride 140 dwords, row stride 20 dwords; u1 = rows 4..7
      const int base0 = c * 140 + lq * 20 + lm;
      bfi4 u0, u1;
      u0.i.x = tpB[base0];      u0.i.y = tpB[base0 + 1];
      u0.i.z = tpB[base0 + 2];  u0.i.w = tpB[base0 + 3];
      u1.i.x = tpB[base0 + 80]; u1.i.y = tpB[base0 + 81];
      u1.i.z = tpB[base0 + 82]; u1.i.w = tpB[base0 + 83];

      ffrag h0 = {0.f, 0.f, 0.f, 0.f}, h1 = {0.f, 0.f, 0.f, 0.f};
      h0 = __builtin_amdgcn_mfma_f32_16x16x32_bf16(u0.b, cw[0][0], h0, 0, 0, 0);
      h0 = __builtin_amdgcn_mfma_f32_16x16x32_bf16(u1.b, cw[1][0], h0, 0, 0, 0);
      h1 = __builtin_amdgcn_mfma_f32_16x16x32_bf16(u0.b, cw[0][1], h1, 0, 0, 0);
      h1 = __builtin_amdgcn_mfma_f32_16x16x32_bf16(u1.b, cw[1][1], h1, 0, 0, 0);

      // h0/h1: row = pixel m = lq*4+rr, col o = {lm, 16+lm}
#pragma unroll
      for (int rr = 0; rr < 4; ++rr) {
        float v = gelu_f(h0[rr] + hb1v[0]) * hw2v[0] +
                  gelu_f(h1[rr] + hb1v[1]) * hw2v[1];
        v = reduce16(v);
        const int p = 2 * (lq * 4 + rr) + par;
        const float res = bf2f(sX[c * 280 + 123 + p]);  // x center tap (row 3)
        if (lm == 0) sM[p * 34 + c] = f2bf_fast(v + hb2n + res);
      }
    }
  }
  __syncthreads();

  // ---- phase B: fused MLP 32->512(gelu)->256(gelu)->32 (+residual),
  // split-K: t1 in two 256-col halves. sT2 aliases sT1h (barrier-separated).
  short* sT1h = (short*)smem;
  short* sT2  = (short*)smem;
  const int wave = n;
  const int koff = lq * 8;
  const int mt3 = wave & 1;
  const int nt3 = wave >> 1;
  const int col3 = nt3 * 16 + lm;
  const int pixg = (b * 128 + h) * 256 + w0;

  const int n0 = wave * 4;
  ffrag acc[2][4];
#pragma unroll
  for (int mt = 0; mt < 2; ++mt)
#pragma unroll
    for (int ni = 0; ni < 4; ++ni) acc[mt][ni] = ffrag{0.f, 0.f, 0.f, 0.f};
  const short* w2base = fw2s + n0 * 512 + lane * 8;

#pragma unroll 1
  for (int H = 0; H < 2; ++H) {
    // layer 1, half H: waves produce cols [H*256, H*256+256)
    // aF reloaded per half (sM stable) -> dead during layer 2
    bfrag aF[2];
#pragma unroll
    for (int mt = 0; mt < 2; ++mt)
      aF[mt] = *(const bfrag*)(sM + (mt * 16 + lm) * 34 + koff);
#pragma unroll
    for (int ni = 0; ni < 4; ++ni) {
      const bfrag b1f = *(const bfrag*)(fw1s +
                          (H * 16 + wave * 4 + ni) * 512 + lane * 8);
      const int ntl = wave * 4 + ni;          // within-half tile
#pragma unroll
      for (int mt = 0; mt < 2; ++mt) {
        ffrag cc = {0.f, 0.f, 0.f, 0.f};
        cc = __builtin_amdgcn_mfma_f32_16x16x32_bf16(aF[mt], b1f, cc, 0, 0, 0);
        const int colg = H * 256 + ntl * 16 + lm;
        const float bias = fb1[colg];
#pragma unroll
        for (int r = 0; r < 4; ++r) {
          const int row = mt * 16 + lq * 4 + r;
          sT1h[row * 264 + ntl * 16 + lm] = f2bf_fast(gelu_f(cc[r] + bias));
        }
      }
    }
    __syncthreads();

    // layer 2 partial accumulation over this half's K=256
#pragma unroll 2
    for (int kt = 0; kt < 8; ++kt) {
      bfrag bv[4];
#pragma unroll
      for (int ni = 0; ni < 4; ++ni)
        bv[ni] = *(const bfrag*)(w2base + (H * 8 + kt) * 8192 + ni * 512);
      const bfrag a0 = *(const bfrag*)(sT1h + lm * 264 + kt * 32 + koff);
      const bfrag a1 = *(const bfrag*)(sT1h + (16 + lm) * 264 + kt * 32 + koff);
#pragma unroll
      for (int ni = 0; ni < 4; ++ni) {
        acc[0][ni] = __builtin_amdgcn_mfma_f32_16x16x32_bf16(a0, bv[ni], acc[0][ni], 0, 0, 0);
        acc[1][ni] = __builtin_amdgcn_mfma_f32_16x16x32_bf16(a1, bv[ni], acc[1][ni], 0, 0, 0);
      }
    }
    __syncthreads();   // before next half overwrites sT1h
  }

  // t2 epilogue (sT2 == sT1h region; all layer-2 reads drained by barrier)
#pragma unroll
  for (int mt = 0; mt < 2; ++mt)
#pragma unroll
    for (int ni = 0; ni < 4; ++ni) {
      const int col = (n0 + ni) * 16 + lm;
      const float bias = fb2[col];
#pragma unroll
      for (int r = 0; r < 4; ++r) {
        const int row = mt * 16 + lq * 4 + r;
        sT2[row * 264 + col] = f2bf_fast(gelu_f(acc[mt][ni][r] + bias));
      }
    }
  __syncthreads();

  // layer 3 (reads sT2), then barrier, then sO aliases sT2 for the burst
  ffrag c3 = {0.f, 0.f, 0.f, 0.f};
  const short* sA3 = sT2 + (mt3 * 16 + lm) * 264 + koff;
#pragma unroll
  for (int kt = 0; kt < 8; ++kt) {
    const bfrag a = *(const bfrag*)(sA3 + kt * 32);
    const bfrag bw = *(const bfrag*)(fw3s + nt3 * 512 + kt * 1024 + lane * 8);
    c3 = __builtin_amdgcn_mfma_f32_16x16x32_bf16(a, bw, c3, 0, 0, 0);
  }
  __syncthreads();   // all sT2 reads done before sO overwrite
  {
    const float bias = fb3[col3];
#pragma unroll
    for (int r = 0; r < 4; ++r) {
      const int row = mt3 * 16 + lq * 4 + r;
      const float res = bf2f(sM[(mt3 * 16 + lq * 4 + r) * 34 + col3]);
      sO[row * 34 + col3] = c3[r] + bias + res;
    }
  }
  if (tid < 32) {   // sincos passthrough, loaded late (x row L2-hot)
    const float2 scv =
        *(const float2*)&x[(size_t)(((b * 128 + h) * 256 + w0 + tid)) * 34 + 32];
    sO[tid * 34 + 32] = scv.x;
    sO[tid * 34 + 33] = scv.y;
  }
  __syncthreads();
  {
    const float4* sp = (const float4*)sO;           // 1088 floats = 272 f4
    float4* dp = (float4*)(outb + (size_t)pixg * 34);
    for (int e = tid; e < 272; e += 256) dp[e] = sp[e];
  }
}

// ---------------------------------------------------------------------------
extern "C" void kernel_launch(void* const* d_in, const int* in_sizes, int n_in,
                              void* d_out, int out_size, void* d_ws, size_t ws_size,
                              hipStream_t stream) {
  const float* x   = (const float*)d_in[0];
  const float* psi = (const float*)d_in[1];
  const float* dw  = (const float*)d_in[2];
  const float* db  = (const float*)d_in[3];
  const float* hw1 = (const float*)d_in[4];
  const float* hb1 = (const float*)d_in[5];
  const float* hw2 = (const float*)d_in[6];
  const float* hb2 = (const float*)d_in[7];
  const float* fw1 = (const float*)d_in[8];
  const float* fb1 = (const float*)d_in[9];
  const float* fw2 = (const float*)d_in[10];
  const float* fb2 = (const float*)d_in[11];
  const float* fw3 = (const float*)d_in[12];
  const float* fb3 = (const float*)d_in[13];
  float* outb = (float*)d_out;

  // workspace (~4.5 MB)
  short* wcb  = (short*)d_ws;        // 128*16384 = 2097152 shorts
  short* fw1s = wcb + 2097152;       // 16384
  short* fw2s = fw1s + 16384;        // 131072
  short* fw3s = fw2s + 131072;       // 8192
  float* hb1e = (float*)(fw3s + 8192);  // 128 floats

  hipLaunchKernelGGL(k01_prep, dim3(532), dim3(256), 0, stream,
                     psi, dw, db, fw1, fw2, fw3, hw1, hb1,
                     wcb, fw1s, fw2s, fw3s, hb1e);
  hipLaunchKernelGGL(k23_fused, dim3(8, 128, 2), dim3(256), 0, stream,
                     x, wcb, hb1e, hw2, hb2,
                     fw1s, fw2s, fw3s, fb1, fb2, fb3, outb);
}

// Round 5
// 168.812 us; speedup vs baseline: 1.0959x; 1.0015x over previous
//
#include <hip/hip_runtime.h>
#include <math.h>

// Problem constants
// B=2, H=128, W=256, MD=34, LD=32, NH=4, HD=8, SH=64, K=25, P=7, R=3,
// FF1=512, FF2=256

typedef __attribute__((ext_vector_type(8))) short bfrag;    // 8 bf16 = 4 VGPR
typedef __attribute__((ext_vector_type(4))) float ffrag;    // 4 f32 acc
typedef __attribute__((ext_vector_type(4))) short short4v;  // 8B

union bfi4 { int4 i; bfrag b; };

// Fast tanh-form GELU (~7 VALU ops, |err| vs erf-GELU ~3e-3)
__device__ __forceinline__ float gelu_f(float v) {
  const float z = v * (2.3022077484f + 0.1029451564f * v * v);  // log2e folded
  const float e = __builtin_amdgcn_exp2f(-z);
  return v * __builtin_amdgcn_rcpf(1.0f + e);
}

// exact RNE (cold paths: weight prep)
__device__ __forceinline__ short f2bf(float f) {
  union { float f; unsigned u; } v; v.f = f;
  unsigned r = (v.u + 0x7fffu + ((v.u >> 16) & 1u)) >> 16;
  return (short)r;
}

// round-half-up (2 VALU ops)
__device__ __forceinline__ short f2bf_fast(float f) {
  union { float f; unsigned u; } v; v.f = f;
  return (short)((v.u + 0x8000u) >> 16);
}

__device__ __forceinline__ float bf2f(short s) {
  union { float f; unsigned u; } v;
  v.u = ((unsigned)(unsigned short)s) << 16;
  return v.f;
}

// DPP cross-lane add; butterfly reduction over 16 lanes (all lanes get sum).
template <int CTRL>
__device__ __forceinline__ float dpp_add(float v) {
  union { float f; int i; } s, t;
  s.f = v;
  t.i = __builtin_amdgcn_update_dpp(0, s.i, CTRL, 0xf, 0xf, true);
  return v + t.f;
}
__device__ __forceinline__ float reduce16(float v) {
  v = dpp_add<0xB1>(v);    // quad_perm [1,0,3,2]  = xor1
  v = dpp_add<0x4E>(v);    // quad_perm [2,3,0,1]  = xor2
  v = dpp_add<0x141>(v);   // row_half_mirror      ~ xor4 after fold
  v = dpp_add<0x140>(v);   // row_mirror           ~ xor8 after fold
  return v;
}

// staged bf16 short4 store helper
__device__ __forceinline__ void st4bf(short* p, float4 v) {
  short4v s;
  s[0] = f2bf(v.x); s[1] = f2bf(v.y); s[2] = f2bf(v.z); s[3] = f2bf(v.w);
  *(short4v*)p = s;
}

// XCD-aware bijective remap (8 XCDs x 256 slots; 16 slots share one h)
__device__ __forceinline__ void tile_map(int& w0, int& b, int& h, int& lin) {
  lin  = blockIdx.x + (blockIdx.y << 3) + (blockIdx.z << 10);
  const int xcd  = lin & 7;
  const int slot = lin >> 3;
  w0 = (slot & 7) * 32;
  b  = (slot >> 3) & 1;
  h  = (xcd << 4) | (slot >> 4);
}

// ---------------------------------------------------------------------------
// K01: weight prep (unchanged from round 4).
// ---------------------------------------------------------------------------
__global__ __launch_bounds__(256) void k01_prep(
    const float* __restrict__ psi, const float* __restrict__ dw,
    const float* __restrict__ db,
    const float* __restrict__ fw1, const float* __restrict__ fw2,
    const float* __restrict__ fw3, const float* __restrict__ hw1,
    const float* __restrict__ hb1,
    short* __restrict__ wcb, short* __restrict__ fw1s,
    short* __restrict__ fw2s, short* __restrict__ fw3s,
    float* __restrict__ hb1e) {
  __shared__ __align__(16) char sm[24832];
  const int bid = blockIdx.x;
  const int tid = threadIdx.x;

  if (bid < 512) {            // ---- fused conv+MLP1 fragments per (h, n)
    float* tileL = (float*)sm;               // [64][52] f32   = 13312 B
    float* hw1n  = (float*)(sm + 13312);     // [64][32] f32   =  8192 B
    short* tile2 = (short*)(sm + 21504);     // [32][52] bf16  =  3328 B
    const int h = bid >> 2;
    const int n = bid & 3;
    const int lane = tid & 63;
    const int w = __builtin_amdgcn_readfirstlane(tid >> 6);

    for (int e = tid; e < 512; e += 256)
      ((float4*)hw1n)[e] = ((const float4*)(hw1 + n * 2048))[e];

    float dwreg[25];
#pragma unroll
    for (int kk = 0; kk < 25; ++kk) dwreg[kk] = dw[lane * 25 + kk];
    const int p0 = w * 13;
    const int pend = (p0 + 13 < 49) ? (p0 + 13) : 49;
#pragma unroll 1
    for (int p = p0; p < pend; ++p) {
      float acc = 0.f;
#pragma unroll
      for (int kk = 0; kk < 25; ++kk)
        acc += dwreg[kk] * psi[kk * 6272 + h * 49 + p];   // uniform -> s_load
      tileL[lane * 52 + p] = acc;
    }
    __syncthreads();

    const int o = tid & 31;
#pragma unroll 1
    for (int pp = tid >> 5; pp < 25; pp += 8) {
      const int p2 = pp * 2;
      float a0 = 0.f, a1 = 0.f;
#pragma unroll 4
      for (int f = 0; f < 64; ++f) {
        const float wv = hw1n[f * 32 + o];
        a0 += wv * tileL[f * 52 + p2];
        a1 += wv * tileL[f * 52 + p2 + 1];
      }
      tile2[o * 52 + p2] = f2bf(a0);
      if (p2 + 1 < 49) tile2[o * 52 + p2 + 1] = f2bf(a1);
    }
    __syncthreads();

    short* outp = wcb + h * 16384 + n * 4096;
    for (int idx = tid; idx < 4096; idx += 256) {
      const int jj = idx & 7, ln = (idx >> 3) & 63;
      const int nt = (idx >> 9) & 1, kt = (idx >> 10) & 1;
      const int par = idx >> 11;
      const int k = kt * 32 + ((ln >> 4) << 3) + jj;
      const int oo = nt * 16 + (ln & 15);
      const int r = k >> 3, dlt = k & 7;
      const int j = par ? (dlt - 1) : dlt;
      short v = 0;
      if (r < 7 && j >= 0 && j < 7) v = tile2[oo * 52 + r * 7 + j];
      outp[idx] = v;
    }
    return;
  }

  if (bid < 528) {            // ---- fw2 kt-tile transpose: K rows 32, N 256
    short* S = (short*)sm;               // [32][260]
    const int kt = bid - 512;
    const float* src = fw2 + kt * 8192;
    for (int q = tid; q < 2048; q += 256) {
      const int lin = q * 4;
      const int kk = lin >> 8, nn = lin & 255;
      st4bf(S + kk * 260 + nn, *(const float4*)(src + lin));
    }
    __syncthreads();
    short* dst = fw2s + kt * 8192;
    for (int q = tid; q < 8192; q += 256) {
      const int jj = q & 7, lane = (q >> 3) & 63, nt = q >> 9;
      const int kk = (lane >> 4) * 8 + jj, nn = nt * 16 + (lane & 15);
      dst[q] = S[kk * 260 + nn];
    }
    return;
  }

  if (bid < 530) {            // ---- fw1 transpose half X: K 32, N 256
    const int X = bid - 528;
    short* S = (short*)sm;               // [32][260]
    for (int q = tid; q < 2048; q += 256) {
      const int lin = q * 4;
      const int kk = lin >> 8, nn = lin & 255;
      st4bf(S + kk * 260 + nn, *(const float4*)(fw1 + kk * 512 + X * 256 + nn));
    }
    __syncthreads();
    for (int q = tid; q < 8192; q += 256) {
      const int jj = q & 7, lane = (q >> 3) & 63, ntl = q >> 9;
      const int kk = (lane >> 4) * 8 + jj, nn = ntl * 16 + (lane & 15);
      fw1s[X * 8192 + q] = S[kk * 260 + nn];
    }
    return;
  }

  if (bid == 530) {           // ---- fw3 transpose: K 256, N 32
    short* S = (short*)sm;               // [256][36]
    for (int q = tid; q < 2048; q += 256) {
      const int lin = q * 4;
      const int kk = lin >> 5, nn = lin & 31;
      st4bf(S + kk * 36 + nn, *(const float4*)(fw3 + lin));
    }
    __syncthreads();
    for (int q = tid; q < 8192; q += 256) {
      const int jj = q & 7, lane = (q >> 3) & 63;
      const int nt = (q >> 9) & 1, kt = q >> 10;
      const int kk = kt * 32 + (lane >> 4) * 8 + jj, nn = nt * 16 + (lane & 15);
      fw3s[q] = S[kk * 36 + nn];
    }
    return;
  }

  // ---- bid 531: hb1e[n][o] = hb1[n][o] + sum_s hw1[n][s][o]*db[s] (exact)
  if (tid < 128) {
    const int n = tid >> 5, o = tid & 31;
    float acc = hb1[n * 32 + o];
#pragma unroll
    for (int s = 0; s < 64; ++s)
      acc += hw1[n * 2048 + s * 32 + o] * db[s];
    hb1e[tid] = acc;
  }
}

// ---------------------------------------------------------------------------
// K2: DISCO conv (hw1-folded) + head-MLP tail -> wsM (bf16 [32][32] tiles).
// Split from the old fused k23: without phase B's 32-AGPR accumulator this
// kernel fits the 64-reg budget (~44 total) -> TRUE 8 blocks/CU, the whole
// 2048-block grid resident in ONE generation (round-4 counters: 7/CU + a
// lone-block tail = 45% of wall at occ 54%).
// LDS 20384 B (sX 18080 incl guard + sM [32][36] 2304) -> alloc 20480,
// 8 x 20480 = exactly 160 KiB.
// ---------------------------------------------------------------------------
__global__ __launch_bounds__(256, 8) void k2_conv(
    const float* __restrict__ x,    const short* __restrict__ wcb,
    const float* __restrict__ hb1e, const float* __restrict__ hw2,
    const float* __restrict__ hb2,  short* __restrict__ wsM) {
  __shared__ __align__(16) char smem[20384];
  short* sX = (short*)smem;                  // [32 ch][280] bf16 + guard
  short* sM = (short*)(smem + 18080);        // [32][36] bf16

  const int tid = threadIdx.x;
  int w0, b, h, lin;
  tile_map(w0, b, h, lin);

  const int lane = tid & 63, lm = lane & 15, lq = lane >> 4;
  const int n = tid >> 6;  // wave == head

  float hb1v[2], hw2v[2];
#pragma unroll
  for (int nt = 0; nt < 2; ++nt) {
    hb1v[nt] = hb1e[n * 32 + nt * 16 + lm];
    hw2v[nt] = hw2[n * 32 + nt * 16 + lm];
  }
  const float hb2n = hb2[n];

  {  // zero-fill whole LDS (tap pads must be 0.0bf16, never garbage)
    int4* p = (int4*)smem;
    int4 z; z.x = z.y = z.z = z.w = 0;
    for (int e = tid; e < 20384 / 16; e += 256) p[e] = z;
  }
  __syncthreads();

  // stage x tile as bf16; channel stride 280 shorts, row stride 40 shorts
#pragma unroll 1
  for (int r = 0; r < 7; ++r) {
    int hr = h - 3 + r; hr = hr < 0 ? 0 : (hr > 127 ? 127 : hr);
    const float* __restrict__ xrow = x + (size_t)((b * 128 + hr) * 256) * 34;
    short* __restrict__ sxr = sX + r * 40;
    for (int e = tid; e < 39 * 16; e += 256) {
      const int c2 = e & 15;
      const int wp = e >> 4;
      const int wr = (w0 - 3 + wp) & 255;
      const float2 v = *(const float2*)&xrow[wr * 34 + c2 * 2];
      short* dp = sxr + (c2 * 2) * 280 + wp;
      dp[0]   = f2bf_fast(v.x);
      dp[280] = f2bf_fast(v.y);
    }
  }
  __syncthreads();

  const int* tpB = (const int*)sX;

  // par-outer: one parity's cW (16 VGPRs) live at a time
#pragma unroll 1
  for (int par = 0; par < 2; ++par) {
    bfrag cw[2][2];
#pragma unroll
    for (int kt = 0; kt < 2; ++kt)
#pragma unroll
      for (int nt = 0; nt < 2; ++nt)
        cw[kt][nt] = *(const bfrag*)(wcb + h * 16384 + n * 4096 +
                         ((par * 2 + kt) * 2 + nt) * 512 + lane * 8);

#pragma unroll 1
    for (int i = 0; i < 8; ++i) {
      const int c = n * 8 + i;

      // tap A-frags: ch stride 140 dwords, row stride 20; u1 = rows 4..7
      const int base0 = c * 140 + lq * 20 + lm;
      bfi4 u0, u1;
      u0.i.x = tpB[base0];      u0.i.y = tpB[base0 + 1];
      u0.i.z = tpB[base0 + 2];  u0.i.w = tpB[base0 + 3];
      u1.i.x = tpB[base0 + 80]; u1.i.y = tpB[base0 + 81];
      u1.i.z = tpB[base0 + 82]; u1.i.w = tpB[base0 + 83];

      ffrag h0 = {0.f, 0.f, 0.f, 0.f}, h1 = {0.f, 0.f, 0.f, 0.f};
      h0 = __builtin_amdgcn_mfma_f32_16x16x32_bf16(u0.b, cw[0][0], h0, 0, 0, 0);
      h0 = __builtin_amdgcn_mfma_f32_16x16x32_bf16(u1.b, cw[1][0], h0, 0, 0, 0);
      h1 = __builtin_amdgcn_mfma_f32_16x16x32_bf16(u0.b, cw[0][1], h1, 0, 0, 0);
      h1 = __builtin_amdgcn_mfma_f32_16x16x32_bf16(u1.b, cw[1][1], h1, 0, 0, 0);

      // h0/h1: row = pixel m = lq*4+rr, col o = {lm, 16+lm}
#pragma unroll
      for (int rr = 0; rr < 4; ++rr) {
        float v = gelu_f(h0[rr] + hb1v[0]) * hw2v[0] +
                  gelu_f(h1[rr] + hb1v[1]) * hw2v[1];
        v = reduce16(v);
        const int p = 2 * (lq * 4 + rr) + par;
        const float res = bf2f(sX[c * 280 + 123 + p]);  // x center tap (row 3)
        if (lm == 0) sM[p * 36 + c] = f2bf_fast(v + hb2n + res);
      }
    }
  }
  __syncthreads();

  // coalesced sM tile -> workspace (2 KB/tile)
  {
    const int row = tid >> 3, c4 = (tid & 7) * 4;
    *(short4v*)(wsM + lin * 1024 + tid * 4) = *(const short4v*)(sM + row * 36 + c4);
  }
}

// ---------------------------------------------------------------------------
// K3: final MLP 32->512(gelu)->256(gelu)->32 (+residual) from wsM tiles.
// acc[2][4] = 32 AGPR + lean arch set (per-mt aF reload, bv in pairs,
// kt unroll 1) -> fits 64 total -> 8 blocks/CU, one generation.
// LDS 19200 B (sT1h/sT2 [0,16896) + sMv [16896,19200), stride 36 = 18
// dwords: step-18 mod 32 across the 16 lm lanes -> conflict-free aF reads).
// sO f32 [32][34] aliases sT1h behind a barrier.
// ---------------------------------------------------------------------------
__global__ __launch_bounds__(256, 8) void k3_mlp(
    const float* __restrict__ x,    const short* __restrict__ wsM,
    const short* __restrict__ fw1s, const short* __restrict__ fw2s,
    const short* __restrict__ fw3s,
    const float* __restrict__ fb1,  const float* __restrict__ fb2,
    const float* __restrict__ fb3,  float* __restrict__ outb) {
  __shared__ __align__(16) char smem[19200];
  short* sT1h = (short*)smem;                // [32][264] bf16
  short* sT2  = (short*)smem;                // alias (barrier-separated)
  float* sO   = (float*)smem;                // [32][34] f32 (epilogue)
  short* sMv  = (short*)(smem + 16896);      // [32][36] bf16

  const int tid = threadIdx.x;
  int w0, b, h, lin;
  tile_map(w0, b, h, lin);

  const int lane = tid & 63, lm = lane & 15, lq = lane >> 4;
  const int wave = tid >> 6;
  const int koff = lq * 8;

  {  // stage sM tile (coalesced 8B loads; L2-hot from k2 on same XCD)
    const int row = tid >> 3, c4 = (tid & 7) * 4;
    *(short4v*)(sMv + row * 36 + c4) = *(const short4v*)(wsM + lin * 1024 + tid * 4);
  }
  __syncthreads();

  const int mt3 = wave & 1;
  const int nt3 = wave >> 1;
  const int col3 = nt3 * 16 + lm;
  const int pixg = (b * 128 + h) * 256 + w0;
  const int n0 = wave * 4;

  ffrag acc[2][4];
#pragma unroll
  for (int mt = 0; mt < 2; ++mt)
#pragma unroll
    for (int ni = 0; ni < 4; ++ni) acc[mt][ni] = ffrag{0.f, 0.f, 0.f, 0.f};
  const short* w2base = fw2s + n0 * 512 + lane * 8;

#pragma unroll 1
  for (int H = 0; H < 2; ++H) {
    // layer 1, half H: waves produce cols [H*256, H*256+256)
#pragma unroll
    for (int ni = 0; ni < 4; ++ni) {
      const bfrag b1f = *(const bfrag*)(fw1s +
                          (H * 16 + wave * 4 + ni) * 512 + lane * 8);
      const int ntl = wave * 4 + ni;
#pragma unroll
      for (int mt = 0; mt < 2; ++mt) {
        const bfrag aFm = *(const bfrag*)(sMv + (mt * 16 + lm) * 36 + koff);
        ffrag cc = {0.f, 0.f, 0.f, 0.f};
        cc = __builtin_amdgcn_mfma_f32_16x16x32_bf16(aFm, b1f, cc, 0, 0, 0);
        const float bias = fb1[H * 256 + ntl * 16 + lm];
#pragma unroll
        for (int r = 0; r < 4; ++r) {
          const int row = mt * 16 + lq * 4 + r;
          sT1h[row * 264 + ntl * 16 + lm] = f2bf_fast(gelu_f(cc[r] + bias));
        }
      }
    }
    __syncthreads();

    // layer 2 partial accumulation over this half's K=256 (bv in pairs)
#pragma unroll 1
    for (int kt = 0; kt < 8; ++kt) {
      const bfrag a0 = *(const bfrag*)(sT1h + lm * 264 + kt * 32 + koff);
      const bfrag a1 = *(const bfrag*)(sT1h + (16 + lm) * 264 + kt * 32 + koff);
#pragma unroll
      for (int np = 0; np < 2; ++np) {
        const bfrag bv0 = *(const bfrag*)(w2base + (H * 8 + kt) * 8192 + (2 * np) * 512);
        const bfrag bv1 = *(const bfrag*)(w2base + (H * 8 + kt) * 8192 + (2 * np + 1) * 512);
        acc[0][2 * np]     = __builtin_amdgcn_mfma_f32_16x16x32_bf16(a0, bv0, acc[0][2 * np], 0, 0, 0);
        acc[1][2 * np]     = __builtin_amdgcn_mfma_f32_16x16x32_bf16(a1, bv0, acc[1][2 * np], 0, 0, 0);
        acc[0][2 * np + 1] = __builtin_amdgcn_mfma_f32_16x16x32_bf16(a0, bv1, acc[0][2 * np + 1], 0, 0, 0);
        acc[1][2 * np + 1] = __builtin_amdgcn_mfma_f32_16x16x32_bf16(a1, bv1, acc[1][2 * np + 1], 0, 0, 0);
      }
    }
    __syncthreads();   // before next half overwrites sT1h
  }

  // t2 epilogue (sT2 == sT1h region; all layer-2 reads drained by barrier)
#pragma unroll
  for (int mt = 0; mt < 2; ++mt)
#pragma unroll
    for (int ni = 0; ni < 4; ++ni) {
      const int col = (n0 + ni) * 16 + lm;
      const float bias = fb2[col];
#pragma unroll
      for (int r = 0; r < 4; ++r) {
        const int row = mt * 16 + lq * 4 + r;
        sT2[row * 264 + col] = f2bf_fast(gelu_f(acc[mt][ni][r] + bias));
      }
    }
  __syncthreads();

  // layer 3 (reads sT2), then barrier, then sO aliases sT2 for the burst
  ffrag c3 = {0.f, 0.f, 0.f, 0.f};
  const short* sA3 = sT2 + (mt3 * 16 + lm) * 264 + koff;
#pragma unroll
  for (int kt = 0; kt < 8; ++kt) {
    const bfrag a = *(const bfrag*)(sA3 + kt * 32);
    const bfrag bw = *(const bfrag*)(fw3s + nt3 * 512 + kt * 1024 + lane * 8);
    c3 = __builtin_amdgcn_mfma_f32_16x16x32_bf16(a, bw, c3, 0, 0, 0);
  }
  __syncthreads();   // all sT2 reads done before sO overwrite
  {
    const float bias = fb3[col3];
#pragma unroll
    for (int r = 0; r < 4; ++r) {
      const int row = mt3 * 16 + lq * 4 + r;
      const float res = bf2f(sMv[row * 36 + col3]);
      sO[row * 34 + col3] = c3[r] + bias + res;
    }
  }
  if (tid < 32) {   // sincos passthrough (x row L2-hot)
    const float2 scv =
        *(const float2*)&x[(size_t)(((b * 128 + h) * 256 + w0 + tid)) * 34 + 32];
    sO[tid * 34 + 32] = scv.x;
    sO[tid * 34 + 33] = scv.y;
  }
  __syncthreads();
  {
    const float4* sp = (const float4*)sO;           // 1088 floats = 272 f4
    float4* dp = (float4*)(outb + (size_t)pixg * 34);
    for (int e = tid; e < 272; e += 256) dp[e] = sp[e];
  }
}

// ---------------------------------------------------------------------------
extern "C" void kernel_launch(void* const* d_in, const int* in_sizes, int n_in,
                              void* d_out, int out_size, void* d_ws, size_t ws_size,
                              hipStream_t stream) {
  const float* x   = (const float*)d_in[0];
  const float* psi = (const float*)d_in[1];
  const float* dw  = (const float*)d_in[2];
  const float* db  = (const float*)d_in[3];
  const float* hw1 = (const float*)d_in[4];
  const float* hb1 = (const float*)d_in[5];
  const float* hw2 = (const float*)d_in[6];
  const float* hb2 = (const float*)d_in[7];
  const float* fw1 = (const float*)d_in[8];
  const float* fb1 = (const float*)d_in[9];
  const float* fw2 = (const float*)d_in[10];
  const float* fb2 = (const float*)d_in[11];
  const float* fw3 = (const float*)d_in[12];
  const float* fb3 = (const float*)d_in[13];
  float* outb = (float*)d_out;

  // workspace (~8.7 MB)
  short* wcb  = (short*)d_ws;        // 128*16384 = 2097152 shorts
  short* fw1s = wcb + 2097152;       // 16384
  short* fw2s = fw1s + 16384;        // 131072
  short* fw3s = fw2s + 131072;       // 8192
  float* hb1e = (float*)(fw3s + 8192);     // 128 floats
  short* wsM  = (short*)(hb1e + 128);      // 2048*1024 = 2097152 shorts

  hipLaunchKernelGGL(k01_prep, dim3(532), dim3(256), 0, stream,
                     psi, dw, db, fw1, fw2, fw3, hw1, hb1,
                     wcb, fw1s, fw2s, fw3s, hb1e);
  hipLaunchKernelGGL(k2_conv, dim3(8, 128, 2), dim3(256), 0, stream,
                     x, wcb, hb1e, hw2, hb2, wsM);
  hipLaunchKernelGGL(k3_mlp, dim3(8, 128, 2), dim3(256), 0, stream,
                     x, wsM, fw1s, fw2s, fw3s, fb1, fb2, fb3, outb);
}

// Round 6
// 166.301 us; speedup vs baseline: 1.1124x; 1.0151x over previous
//
#include <hip/hip_runtime.h>
#include <math.h>

// Problem constants
// B=2, H=128, W=256, MD=34, LD=32, NH=4, HD=8, SH=64, K=25, P=7, R=3,
// FF1=512, FF2=256

typedef __attribute__((ext_vector_type(8))) short bfrag;    // 8 bf16 = 4 VGPR
typedef __attribute__((ext_vector_type(4))) float ffrag;    // 4 f32 acc
typedef __attribute__((ext_vector_type(4))) short short4v;  // 8B

union bfi4 { int4 i; bfrag b; };

// Fast tanh-form GELU (~7 VALU ops, |err| vs erf-GELU ~3e-3)
__device__ __forceinline__ float gelu_f(float v) {
  const float z = v * (2.3022077484f + 0.1029451564f * v * v);  // log2e folded
  const float e = __builtin_amdgcn_exp2f(-z);
  return v * __builtin_amdgcn_rcpf(1.0f + e);
}

// exact RNE (cold paths: weight prep)
__device__ __forceinline__ short f2bf(float f) {
  union { float f; unsigned u; } v; v.f = f;
  unsigned r = (v.u + 0x7fffu + ((v.u >> 16) & 1u)) >> 16;
  return (short)r;
}

// round-half-up (2 VALU ops)
__device__ __forceinline__ short f2bf_fast(float f) {
  union { float f; unsigned u; } v; v.f = f;
  return (short)((v.u + 0x8000u) >> 16);
}

__device__ __forceinline__ float bf2f(short s) {
  union { float f; unsigned u; } v;
  v.u = ((unsigned)(unsigned short)s) << 16;
  return v.f;
}

// DPP cross-lane add; butterfly reduction over 16 lanes (all lanes get sum).
template <int CTRL>
__device__ __forceinline__ float dpp_add(float v) {
  union { float f; int i; } s, t;
  s.f = v;
  t.i = __builtin_amdgcn_update_dpp(0, s.i, CTRL, 0xf, 0xf, true);
  return v + t.f;
}
__device__ __forceinline__ float reduce16(float v) {
  v = dpp_add<0xB1>(v);    // quad_perm [1,0,3,2]  = xor1
  v = dpp_add<0x4E>(v);    // quad_perm [2,3,0,1]  = xor2
  v = dpp_add<0x141>(v);   // row_half_mirror      ~ xor4 after fold
  v = dpp_add<0x140>(v);   // row_mirror           ~ xor8 after fold
  return v;
}

// staged bf16 short4 store helper
__device__ __forceinline__ void st4bf(short* p, float4 v) {
  short4v s;
  s[0] = f2bf(v.x); s[1] = f2bf(v.y); s[2] = f2bf(v.z); s[3] = f2bf(v.w);
  *(short4v*)p = s;
}

// XCD-aware bijective remap (8 XCDs x 256 slots; 16 slots share one h)
__device__ __forceinline__ void tile_map(int& w0, int& b, int& h, int& lin) {
  lin  = blockIdx.x + (blockIdx.y << 3) + (blockIdx.z << 10);
  const int xcd  = lin & 7;
  const int slot = lin >> 3;
  w0 = (slot & 7) * 32;
  b  = (slot >> 3) & 1;
  h  = (xcd << 4) | (slot >> 4);
}

// ---------------------------------------------------------------------------
// K01: weight prep (unchanged).
// ---------------------------------------------------------------------------
__global__ __launch_bounds__(256) void k01_prep(
    const float* __restrict__ psi, const float* __restrict__ dw,
    const float* __restrict__ db,
    const float* __restrict__ fw1, const float* __restrict__ fw2,
    const float* __restrict__ fw3, const float* __restrict__ hw1,
    const float* __restrict__ hb1,
    short* __restrict__ wcb, short* __restrict__ fw1s,
    short* __restrict__ fw2s, short* __restrict__ fw3s,
    float* __restrict__ hb1e) {
  __shared__ __align__(16) char sm[24832];
  const int bid = blockIdx.x;
  const int tid = threadIdx.x;

  if (bid < 512) {            // ---- fused conv+MLP1 fragments per (h, n)
    float* tileL = (float*)sm;               // [64][52] f32   = 13312 B
    float* hw1n  = (float*)(sm + 13312);     // [64][32] f32   =  8192 B
    short* tile2 = (short*)(sm + 21504);     // [32][52] bf16  =  3328 B
    const int h = bid >> 2;
    const int n = bid & 3;
    const int lane = tid & 63;
    const int w = __builtin_amdgcn_readfirstlane(tid >> 6);

    for (int e = tid; e < 512; e += 256)
      ((float4*)hw1n)[e] = ((const float4*)(hw1 + n * 2048))[e];

    float dwreg[25];
#pragma unroll
    for (int kk = 0; kk < 25; ++kk) dwreg[kk] = dw[lane * 25 + kk];
    const int p0 = w * 13;
    const int pend = (p0 + 13 < 49) ? (p0 + 13) : 49;
#pragma unroll 1
    for (int p = p0; p < pend; ++p) {
      float acc = 0.f;
#pragma unroll
      for (int kk = 0; kk < 25; ++kk)
        acc += dwreg[kk] * psi[kk * 6272 + h * 49 + p];   // uniform -> s_load
      tileL[lane * 52 + p] = acc;
    }
    __syncthreads();

    const int o = tid & 31;
#pragma unroll 1
    for (int pp = tid >> 5; pp < 25; pp += 8) {
      const int p2 = pp * 2;
      float a0 = 0.f, a1 = 0.f;
#pragma unroll 4
      for (int f = 0; f < 64; ++f) {
        const float wv = hw1n[f * 32 + o];
        a0 += wv * tileL[f * 52 + p2];
        a1 += wv * tileL[f * 52 + p2 + 1];
      }
      tile2[o * 52 + p2] = f2bf(a0);
      if (p2 + 1 < 49) tile2[o * 52 + p2 + 1] = f2bf(a1);
    }
    __syncthreads();

    short* outp = wcb + h * 16384 + n * 4096;
    for (int idx = tid; idx < 4096; idx += 256) {
      const int jj = idx & 7, ln = (idx >> 3) & 63;
      const int nt = (idx >> 9) & 1, kt = (idx >> 10) & 1;
      const int par = idx >> 11;
      const int k = kt * 32 + ((ln >> 4) << 3) + jj;
      const int oo = nt * 16 + (ln & 15);
      const int r = k >> 3, dlt = k & 7;
      const int j = par ? (dlt - 1) : dlt;
      short v = 0;
      if (r < 7 && j >= 0 && j < 7) v = tile2[oo * 52 + r * 7 + j];
      outp[idx] = v;
    }
    return;
  }

  if (bid < 528) {            // ---- fw2 kt-tile transpose: K rows 32, N 256
    short* S = (short*)sm;               // [32][260]
    const int kt = bid - 512;
    const float* src = fw2 + kt * 8192;
    for (int q = tid; q < 2048; q += 256) {
      const int lin = q * 4;
      const int kk = lin >> 8, nn = lin & 255;
      st4bf(S + kk * 260 + nn, *(const float4*)(src + lin));
    }
    __syncthreads();
    short* dst = fw2s + kt * 8192;
    for (int q = tid; q < 8192; q += 256) {
      const int jj = q & 7, lane = (q >> 3) & 63, nt = q >> 9;
      const int kk = (lane >> 4) * 8 + jj, nn = nt * 16 + (lane & 15);
      dst[q] = S[kk * 260 + nn];
    }
    return;
  }

  if (bid < 530) {            // ---- fw1 transpose half X: K 32, N 256
    const int X = bid - 528;
    short* S = (short*)sm;               // [32][260]
    for (int q = tid; q < 2048; q += 256) {
      const int lin = q * 4;
      const int kk = lin >> 8, nn = lin & 255;
      st4bf(S + kk * 260 + nn, *(const float4*)(fw1 + kk * 512 + X * 256 + nn));
    }
    __syncthreads();
    for (int q = tid; q < 8192; q += 256) {
      const int jj = q & 7, lane = (q >> 3) & 63, ntl = q >> 9;
      const int kk = (lane >> 4) * 8 + jj, nn = ntl * 16 + (lane & 15);
      fw1s[X * 8192 + q] = S[kk * 260 + nn];
    }
    return;
  }

  if (bid == 530) {           // ---- fw3 transpose: K 256, N 32
    short* S = (short*)sm;               // [256][36]
    for (int q = tid; q < 2048; q += 256) {
      const int lin = q * 4;
      const int kk = lin >> 5, nn = lin & 31;
      st4bf(S + kk * 36 + nn, *(const float4*)(fw3 + lin));
    }
    __syncthreads();
    for (int q = tid; q < 8192; q += 256) {
      const int jj = q & 7, lane = (q >> 3) & 63;
      const int nt = (q >> 9) & 1, kt = q >> 10;
      const int kk = kt * 32 + (lane >> 4) * 8 + jj, nn = nt * 16 + (lane & 15);
      fw3s[q] = S[kk * 36 + nn];
    }
    return;
  }

  // ---- bid 531: hb1e[n][o] = hb1[n][o] + sum_s hw1[n][s][o]*db[s] (exact)
  if (tid < 128) {
    const int n = tid >> 5, o = tid & 31;
    float acc = hb1[n * 32 + o];
#pragma unroll
    for (int s = 0; s < 64; ++s)
      acc += hw1[n * 2048 + s * 32 + o] * db[s];
    hb1e[tid] = acc;
  }
}

// ---------------------------------------------------------------------------
// K23 (re-merged): DISCO conv (hw1-folded) + head-MLP tail + final MLP.
// grid (8,128,2), block 256, LDS 20384 B -> alloc 20480, 8 x 20480 = 160 KiB.
// __launch_bounds__(256,8) = cap 64: R5 proved EACH phase fits 64 spill-free
// (k3: arch 32 + acc 32, clean FETCH/WRITE; k2: ~44 total). Merging deletes
// the wsM 8 MB round-trip, the duplicate sM staging, and one launch; phase-
// mixed blocks on a CU break the all-blocks-lockstep barrier convoying that
// the split forced. Spill tell = FETCH/WRITE ballooning vs 9.1/8.7 MB.
// Leanness set: par-outer cW (16 regs), per-mt aF reload, bv in pairs,
// kt unroll 1, res3/sincos deferred to epilogue.
// LDS map: phase A sX [0,18080) + sM [18080,20384); phase B sT1h/sT2
// [0,16896) alias sX (sM survives), sO f32 [0,4352) behind a barrier.
// ---------------------------------------------------------------------------
__global__ __launch_bounds__(256, 8) void k23_fused(
    const float* __restrict__ x,    const short* __restrict__ wcb,
    const float* __restrict__ hb1e, const float* __restrict__ hw2,
    const float* __restrict__ hb2,
    const short* __restrict__ fw1s, const short* __restrict__ fw2s,
    const short* __restrict__ fw3s,
    const float* __restrict__ fb1,  const float* __restrict__ fb2,
    const float* __restrict__ fb3,  float* __restrict__ outb) {
  __shared__ __align__(16) char smem[20384];
  short* sX = (short*)smem;                  // [32 ch][280] bf16 + guard
  short* sM = (short*)(smem + 18080);        // [32][36] bf16

  const int tid = threadIdx.x;
  int w0, b, h, lin;
  tile_map(w0, b, h, lin);

  const int lane = tid & 63, lm = lane & 15, lq = lane >> 4;
  const int n = tid >> 6;  // wave == head in phase A

  float hb1v[2], hw2v[2];
#pragma unroll
  for (int nt = 0; nt < 2; ++nt) {
    hb1v[nt] = hb1e[n * 32 + nt * 16 + lm];
    hw2v[nt] = hw2[n * 32 + nt * 16 + lm];
  }
  const float hb2n = hb2[n];

  {  // zero-fill whole LDS (tap pads must be 0.0bf16, never garbage)
    int4* p = (int4*)smem;
    int4 z; z.x = z.y = z.z = z.w = 0;
    for (int e = tid; e < 20384 / 16; e += 256) p[e] = z;
  }
  __syncthreads();

  // stage x tile as bf16; channel stride 280 shorts, row stride 40 shorts
#pragma unroll 1
  for (int r = 0; r < 7; ++r) {
    int hr = h - 3 + r; hr = hr < 0 ? 0 : (hr > 127 ? 127 : hr);
    const float* __restrict__ xrow = x + (size_t)((b * 128 + hr) * 256) * 34;
    short* __restrict__ sxr = sX + r * 40;
    for (int e = tid; e < 39 * 16; e += 256) {
      const int c2 = e & 15;
      const int wp = e >> 4;
      const int wr = (w0 - 3 + wp) & 255;
      const float2 v = *(const float2*)&xrow[wr * 34 + c2 * 2];
      short* dp = sxr + (c2 * 2) * 280 + wp;
      dp[0]   = f2bf_fast(v.x);
      dp[280] = f2bf_fast(v.y);
    }
  }
  __syncthreads();

  const int* tpB = (const int*)sX;

  // ---- phase A: par-outer (one parity's cW = 16 regs live at a time)
#pragma unroll 1
  for (int par = 0; par < 2; ++par) {
    bfrag cw[2][2];
#pragma unroll
    for (int kt = 0; kt < 2; ++kt)
#pragma unroll
      for (int nt = 0; nt < 2; ++nt)
        cw[kt][nt] = *(const bfrag*)(wcb + h * 16384 + n * 4096 +
                         ((par * 2 + kt) * 2 + nt) * 512 + lane * 8);

#pragma unroll 1
    for (int i = 0; i < 8; ++i) {
      const int c = n * 8 + i;

      // tap A-frags: ch stride 140 dwords, row stride 20; u1 = rows 4..7
      const int base0 = c * 140 + lq * 20 + lm;
      bfi4 u0, u1;
      u0.i.x = tpB[base0];      u0.i.y = tpB[base0 + 1];
      u0.i.z = tpB[base0 + 2];  u0.i.w = tpB[base0 + 3];
      u1.i.x = tpB[base0 + 80]; u1.i.y = tpB[base0 + 81];
      u1.i.z = tpB[base0 + 82]; u1.i.w = tpB[base0 + 83];

      ffrag h0 = {0.f, 0.f, 0.f, 0.f}, h1 = {0.f, 0.f, 0.f, 0.f};
      h0 = __builtin_amdgcn_mfma_f32_16x16x32_bf16(u0.b, cw[0][0], h0, 0, 0, 0);
      h0 = __builtin_amdgcn_mfma_f32_16x16x32_bf16(u1.b, cw[1][0], h0, 0, 0, 0);
      h1 = __builtin_amdgcn_mfma_f32_16x16x32_bf16(u0.b, cw[0][1], h1, 0, 0, 0);
      h1 = __builtin_amdgcn_mfma_f32_16x16x32_bf16(u1.b, cw[1][1], h1, 0, 0, 0);

      // h0/h1: row = pixel m = lq*4+rr, col o = {lm, 16+lm}
#pragma unroll
      for (int rr = 0; rr < 4; ++rr) {
        float v = gelu_f(h0[rr] + hb1v[0]) * hw2v[0] +
                  gelu_f(h1[rr] + hb1v[1]) * hw2v[1];
        v = reduce16(v);
        const int p = 2 * (lq * 4 + rr) + par;
        const float res = bf2f(sX[c * 280 + 123 + p]);  // x center tap (row 3)
        if (lm == 0) sM[p * 36 + c] = f2bf_fast(v + hb2n + res);
      }
    }
  }
  __syncthreads();

  // ---- phase B: fused MLP 32->512(gelu)->256(gelu)->32 (+residual)
  short* sT1h = (short*)smem;
  short* sT2  = (short*)smem;
  float* sO   = (float*)smem;
  const int wave = n;
  const int koff = lq * 8;
  const int mt3 = wave & 1;
  const int nt3 = wave >> 1;
  const int col3 = nt3 * 16 + lm;
  const int pixg = (b * 128 + h) * 256 + w0;
  const int n0 = wave * 4;

  ffrag acc[2][4];
#pragma unroll
  for (int mt = 0; mt < 2; ++mt)
#pragma unroll
    for (int ni = 0; ni < 4; ++ni) acc[mt][ni] = ffrag{0.f, 0.f, 0.f, 0.f};
  const short* w2base = fw2s + n0 * 512 + lane * 8;

#pragma unroll 1
  for (int H = 0; H < 2; ++H) {
    // layer 1, half H: waves produce cols [H*256, H*256+256)
#pragma unroll
    for (int ni = 0; ni < 4; ++ni) {
      const bfrag b1f = *(const bfrag*)(fw1s +
                          (H * 16 + wave * 4 + ni) * 512 + lane * 8);
      const int ntl = wave * 4 + ni;
#pragma unroll
      for (int mt = 0; mt < 2; ++mt) {
        const bfrag aFm = *(const bfrag*)(sM + (mt * 16 + lm) * 36 + koff);
        ffrag cc = {0.f, 0.f, 0.f, 0.f};
        cc = __builtin_amdgcn_mfma_f32_16x16x32_bf16(aFm, b1f, cc, 0, 0, 0);
        const float bias = fb1[H * 256 + ntl * 16 + lm];
#pragma unroll
        for (int r = 0; r < 4; ++r) {
          const int row = mt * 16 + lq * 4 + r;
          sT1h[row * 264 + ntl * 16 + lm] = f2bf_fast(gelu_f(cc[r] + bias));
        }
      }
    }
    __syncthreads();

    // layer 2 partial accumulation over this half's K=256 (bv in pairs)
#pragma unroll 1
    for (int kt = 0; kt < 8; ++kt) {
      const bfrag a0 = *(const bfrag*)(sT1h + lm * 264 + kt * 32 + koff);
      const bfrag a1 = *(const bfrag*)(sT1h + (16 + lm) * 264 + kt * 32 + koff);
#pragma unroll
      for (int np = 0; np < 2; ++np) {
        const bfrag bv0 = *(const bfrag*)(w2base + (H * 8 + kt) * 8192 + (2 * np) * 512);
        const bfrag bv1 = *(const bfrag*)(w2base + (H * 8 + kt) * 8192 + (2 * np + 1) * 512);
        acc[0][2 * np]     = __builtin_amdgcn_mfma_f32_16x16x32_bf16(a0, bv0, acc[0][2 * np], 0, 0, 0);
        acc[1][2 * np]     = __builtin_amdgcn_mfma_f32_16x16x32_bf16(a1, bv0, acc[1][2 * np], 0, 0, 0);
        acc[0][2 * np + 1] = __builtin_amdgcn_mfma_f32_16x16x32_bf16(a0, bv1, acc[0][2 * np + 1], 0, 0, 0);
        acc[1][2 * np + 1] = __builtin_amdgcn_mfma_f32_16x16x32_bf16(a1, bv1, acc[1][2 * np + 1], 0, 0, 0);
      }
    }
    __syncthreads();   // before next half overwrites sT1h
  }

  // t2 epilogue (sT2 == sT1h region; all layer-2 reads drained by barrier)
#pragma unroll
  for (int mt = 0; mt < 2; ++mt)
#pragma unroll
    for (int ni = 0; ni < 4; ++ni) {
      const int col = (n0 + ni) * 16 + lm;
      const float bias = fb2[col];
#pragma unroll
      for (int r = 0; r < 4; ++r) {
        const int row = mt * 16 + lq * 4 + r;
        sT2[row * 264 + col] = f2bf_fast(gelu_f(acc[mt][ni][r] + bias));
      }
    }
  __syncthreads();

  // layer 3 (reads sT2), then barrier, then sO aliases sT2 for the burst
  ffrag c3 = {0.f, 0.f, 0.f, 0.f};
  const short* sA3 = sT2 + (mt3 * 16 + lm) * 264 + koff;
#pragma unroll
  for (int kt = 0; kt < 8; ++kt) {
    const bfrag a = *(const bfrag*)(sA3 + kt * 32);
    const bfrag bw = *(const bfrag*)(fw3s + nt3 * 512 + kt * 1024 + lane * 8);
    c3 = __builtin_amdgcn_mfma_f32_16x16x32_bf16(a, bw, c3, 0, 0, 0);
  }
  __syncthreads();   // all sT2 reads done before sO overwrite
  {
    const float bias = fb3[col3];
#pragma unroll
    for (int r = 0; r < 4; ++r) {
      const int row = mt3 * 16 + lq * 4 + r;
      const float res = bf2f(sM[row * 36 + col3]);
      sO[row * 34 + col3] = c3[r] + bias + res;
    }
  }
  if (tid < 32) {   // sincos passthrough (x row L2-hot)
    const float2 scv =
        *(const float2*)&x[(size_t)(((b * 128 + h) * 256 + w0 + tid)) * 34 + 32];
    sO[tid * 34 + 32] = scv.x;
    sO[tid * 34 + 33] = scv.y;
  }
  __syncthreads();
  {
    const float4* sp = (const float4*)sO;           // 1088 floats = 272 f4
    float4* dp = (float4*)(outb + (size_t)pixg * 34);
    for (int e = tid; e < 272; e += 256) dp[e] = sp[e];
  }
}

// ---------------------------------------------------------------------------
extern "C" void kernel_launch(void* const* d_in, const int* in_sizes, int n_in,
                              void* d_out, int out_size, void* d_ws, size_t ws_size,
                              hipStream_t stream) {
  const float* x   = (const float*)d_in[0];
  const float* psi = (const float*)d_in[1];
  const float* dw  = (const float*)d_in[2];
  const float* db  = (const float*)d_in[3];
  const float* hw1 = (const float*)d_in[4];
  const float* hb1 = (const float*)d_in[5];
  const float* hw2 = (const float*)d_in[6];
  const float* hb2 = (const float*)d_in[7];
  const float* fw1 = (const float*)d_in[8];
  const float* fb1 = (const float*)d_in[9];
  const float* fw2 = (const float*)d_in[10];
  const float* fb2 = (const float*)d_in[11];
  const float* fw3 = (const float*)d_in[12];
  const float* fb3 = (const float*)d_in[13];
  float* outb = (float*)d_out;

  // workspace (~4.5 MB)
  short* wcb  = (short*)d_ws;        // 128*16384 = 2097152 shorts
  short* fw1s = wcb + 2097152;       // 16384
  short* fw2s = fw1s + 16384;        // 131072
  short* fw3s = fw2s + 131072;       // 8192
  float* hb1e = (float*)(fw3s + 8192);  // 128 floats

  hipLaunchKernelGGL(k01_prep, dim3(532), dim3(256), 0, stream,
                     psi, dw, db, fw1, fw2, fw3, hw1, hb1,
                     wcb, fw1s, fw2s, fw3s, hb1e);
  hipLaunchKernelGGL(k23_fused, dim3(8, 128, 2), dim3(256), 0, stream,
                     x, wcb, hb1e, hw2, hb2,
                     fw1s, fw2s, fw3s, fb1, fb2, fb3, outb);
}

// Round 7
// 161.081 us; speedup vs baseline: 1.1485x; 1.0324x over previous
//
#include <hip/hip_runtime.h>
#include <math.h>

// Problem constants
// B=2, H=128, W=256, MD=34, LD=32, NH=4, HD=8, SH=64, K=25, P=7, R=3,
// FF1=512, FF2=256

typedef __attribute__((ext_vector_type(8))) short bfrag;    // 8 bf16 = 4 VGPR
typedef __attribute__((ext_vector_type(4))) float ffrag;    // 4 f32 acc
typedef __attribute__((ext_vector_type(4))) short short4v;  // 8B

union bfi4 { int4 i; bfrag b; };

// Fast tanh-form GELU (~7 VALU ops, |err| vs erf-GELU ~3e-3)
__device__ __forceinline__ float gelu_f(float v) {
  const float z = v * (2.3022077484f + 0.1029451564f * v * v);  // log2e folded
  const float e = __builtin_amdgcn_exp2f(-z);
  return v * __builtin_amdgcn_rcpf(1.0f + e);
}

// exact RNE (cold paths: weight prep)
__device__ __forceinline__ short f2bf(float f) {
  union { float f; unsigned u; } v; v.f = f;
  unsigned r = (v.u + 0x7fffu + ((v.u >> 16) & 1u)) >> 16;
  return (short)r;
}

// round-half-up (2 VALU ops)
__device__ __forceinline__ short f2bf_fast(float f) {
  union { float f; unsigned u; } v; v.f = f;
  return (short)((v.u + 0x8000u) >> 16);
}

__device__ __forceinline__ float bf2f(short s) {
  union { float f; unsigned u; } v;
  v.u = ((unsigned)(unsigned short)s) << 16;
  return v.f;
}

// pack two f32 -> bf16 pair in one dword: (bf(b)<<16)|bf(a); 3 VALU ops
__device__ __forceinline__ int pkbf(float a, float b) {
  union { float f; unsigned u; } va, vb; va.f = a; vb.f = b;
  return (int)__builtin_amdgcn_perm(vb.u + 0x8000u, va.u + 0x8000u, 0x07060302u);
}

// staged bf16 short4 store helper
__device__ __forceinline__ void st4bf(short* p, float4 v) {
  short4v s;
  s[0] = f2bf(v.x); s[1] = f2bf(v.y); s[2] = f2bf(v.z); s[3] = f2bf(v.w);
  *(short4v*)p = s;
}

// XCD-aware bijective remap (8 XCDs x 256 slots; 16 slots share one h)
__device__ __forceinline__ void tile_map(int& w0, int& b, int& h, int& lin) {
  lin  = blockIdx.x + (blockIdx.y << 3) + (blockIdx.z << 10);
  const int xcd  = lin & 7;
  const int slot = lin >> 3;
  w0 = (slot & 7) * 32;
  b  = (slot >> 3) & 1;
  h  = (xcd << 4) | (slot >> 4);
}

// ---------------------------------------------------------------------------
// K01: weight prep (chain-split accumulators; layouts unchanged).
// ---------------------------------------------------------------------------
__global__ __launch_bounds__(256) void k01_prep(
    const float* __restrict__ psi, const float* __restrict__ dw,
    const float* __restrict__ db,
    const float* __restrict__ fw1, const float* __restrict__ fw2,
    const float* __restrict__ fw3, const float* __restrict__ hw1,
    const float* __restrict__ hb1,
    short* __restrict__ wcb, short* __restrict__ fw1s,
    short* __restrict__ fw2s, short* __restrict__ fw3s,
    float* __restrict__ hb1e) {
  __shared__ __align__(16) char sm[24832];
  const int bid = blockIdx.x;
  const int tid = threadIdx.x;

  if (bid < 512) {            // ---- fused conv+MLP1 fragments per (h, n)
    float* tileL = (float*)sm;               // [64][52] f32   = 13312 B
    float* hw1n  = (float*)(sm + 13312);     // [64][32] f32   =  8192 B
    short* tile2 = (short*)(sm + 21504);     // [32][52] bf16  =  3328 B
    const int h = bid >> 2;
    const int n = bid & 3;
    const int lane = tid & 63;
    const int w = __builtin_amdgcn_readfirstlane(tid >> 6);

    for (int e = tid; e < 512; e += 256)
      ((float4*)hw1n)[e] = ((const float4*)(hw1 + n * 2048))[e];

    float dwreg[25];
#pragma unroll
    for (int kk = 0; kk < 25; ++kk) dwreg[kk] = dw[lane * 25 + kk];
    const int p0 = w * 13;
    const int pend = (p0 + 13 < 49) ? (p0 + 13) : 49;
#pragma unroll 1
    for (int p = p0; p < pend; ++p) {
      float ae = 0.f, ao = 0.f;           // 2 chains (was 1, 25-deep)
#pragma unroll
      for (int kk = 0; kk < 24; kk += 2) {
        ae += dwreg[kk]     * psi[kk * 6272 + h * 49 + p];
        ao += dwreg[kk + 1] * psi[(kk + 1) * 6272 + h * 49 + p];
      }
      ae += dwreg[24] * psi[24 * 6272 + h * 49 + p];
      tileL[lane * 52 + p] = ae + ao;
    }
    __syncthreads();

    const int o = tid & 31;
#pragma unroll 1
    for (int pp = tid >> 5; pp < 25; pp += 8) {
      const int p2 = pp * 2;
      float a0 = 0.f, a1 = 0.f, a2 = 0.f, a3 = 0.f;   // 4 chains
#pragma unroll 4
      for (int f = 0; f < 64; f += 2) {
        const float wv0 = hw1n[f * 32 + o];
        const float wv1 = hw1n[(f + 1) * 32 + o];
        a0 += wv0 * tileL[f * 52 + p2];
        a1 += wv0 * tileL[f * 52 + p2 + 1];
        a2 += wv1 * tileL[(f + 1) * 52 + p2];
        a3 += wv1 * tileL[(f + 1) * 52 + p2 + 1];
      }
      tile2[o * 52 + p2] = f2bf(a0 + a2);
      if (p2 + 1 < 49) tile2[o * 52 + p2 + 1] = f2bf(a1 + a3);
    }
    __syncthreads();

    short* outp = wcb + h * 16384 + n * 4096;
    for (int idx = tid; idx < 4096; idx += 256) {
      const int jj = idx & 7, ln = (idx >> 3) & 63;
      const int nt = (idx >> 9) & 1, kt = (idx >> 10) & 1;
      const int par = idx >> 11;
      const int k = kt * 32 + ((ln >> 4) << 3) + jj;
      const int oo = nt * 16 + (ln & 15);
      const int r = k >> 3, dlt = k & 7;
      const int j = par ? (dlt - 1) : dlt;
      short v = 0;
      if (r < 7 && j >= 0 && j < 7) v = tile2[oo * 52 + r * 7 + j];
      outp[idx] = v;
    }
    return;
  }

  if (bid < 528) {            // ---- fw2 kt-tile transpose: K rows 32, N 256
    short* S = (short*)sm;               // [32][260]
    const int kt = bid - 512;
    const float* src = fw2 + kt * 8192;
    for (int q = tid; q < 2048; q += 256) {
      const int lin = q * 4;
      const int kk = lin >> 8, nn = lin & 255;
      st4bf(S + kk * 260 + nn, *(const float4*)(src + lin));
    }
    __syncthreads();
    short* dst = fw2s + kt * 8192;
    for (int q = tid; q < 8192; q += 256) {
      const int jj = q & 7, lane = (q >> 3) & 63, nt = q >> 9;
      const int kk = (lane >> 4) * 8 + jj, nn = nt * 16 + (lane & 15);
      dst[q] = S[kk * 260 + nn];
    }
    return;
  }

  if (bid < 530) {            // ---- fw1 transpose half X: K 32, N 256
    const int X = bid - 528;
    short* S = (short*)sm;               // [32][260]
    for (int q = tid; q < 2048; q += 256) {
      const int lin = q * 4;
      const int kk = lin >> 8, nn = lin & 255;
      st4bf(S + kk * 260 + nn, *(const float4*)(fw1 + kk * 512 + X * 256 + nn));
    }
    __syncthreads();
    for (int q = tid; q < 8192; q += 256) {
      const int jj = q & 7, lane = (q >> 3) & 63, ntl = q >> 9;
      const int kk = (lane >> 4) * 8 + jj, nn = ntl * 16 + (lane & 15);
      fw1s[X * 8192 + q] = S[kk * 260 + nn];
    }
    return;
  }

  if (bid == 530) {           // ---- fw3 transpose: K 256, N 32
    short* S = (short*)sm;               // [256][36]
    for (int q = tid; q < 2048; q += 256) {
      const int lin = q * 4;
      const int kk = lin >> 5, nn = lin & 31;
      st4bf(S + kk * 36 + nn, *(const float4*)(fw3 + lin));
    }
    __syncthreads();
    for (int q = tid; q < 8192; q += 256) {
      const int jj = q & 7, lane = (q >> 3) & 63;
      const int nt = (q >> 9) & 1, kt = q >> 10;
      const int kk = kt * 32 + (lane >> 4) * 8 + jj, nn = nt * 16 + (lane & 15);
      fw3s[q] = S[kk * 36 + nn];
    }
    return;
  }

  // ---- bid 531: hb1e[n][o] = hb1[n][o] + sum_s hw1[n][s][o]*db[s] (exact)
  if (tid < 128) {
    const int n = tid >> 5, o = tid & 31;
    float acc = hb1[n * 32 + o];
#pragma unroll
    for (int s = 0; s < 64; ++s)
      acc += hw1[n * 2048 + s * 32 + o] * db[s];
    hb1e[tid] = acc;
  }
}

// ---------------------------------------------------------------------------
// K23: DISCO conv (hw1-folded) + head-MLP tail + final MLP.
// grid (8,128,2), block 256, LDS 20384 B, cap 64 (8 blocks/CU).
// R7 changes (VALU-issue-bound per R6: VALUBusy 62%, 63% of it in phase A):
//  * phase A operand SWAP: A=weights, B=taps (frag lane-mappings identical ->
//    k01/gather untouched). D = [o, pixel]: lane holds 8 o for ONE pixel ->
//    o-contraction = 8 in-lane FMA + 2 ds_bpermute + 2 adds (was 4x reduce16
//    = 32 DPP). Biases/hw2 become per-lane float4 loads.
//  * sX row-slot interleave {0,2,4,6,1,3,5}: gather bank-starts {0,8,16,24}/
//    {20,28,4,12} -> perfect 2-way (free); u1 = base+20. Virtual row 7 =
//    slot 7 = next channel slot 0 (zero weights) as before.
//  * phase B layer1/layer2 operand swap too: per-lane 4 consecutive cols ->
//    pkbf-packed b64 stores, float4 bias loads. Reads unchanged by symmetry.
// LDS map: phase A sX [0,18080) + sM [18080,20384); phase B sT1h/sT2
// [0,16896) alias sX (sM survives), sO f32 [0,4352) behind a barrier.
// ---------------------------------------------------------------------------
__global__ __launch_bounds__(256, 8) void k23_fused(
    const float* __restrict__ x,    const short* __restrict__ wcb,
    const float* __restrict__ hb1e, const float* __restrict__ hw2,
    const float* __restrict__ hb2,
    const short* __restrict__ fw1s, const short* __restrict__ fw2s,
    const short* __restrict__ fw3s,
    const float* __restrict__ fb1,  const float* __restrict__ fb2,
    const float* __restrict__ fb3,  float* __restrict__ outb) {
  __shared__ __align__(16) char smem[20384];
  short* sX = (short*)smem;                  // [32 ch][7 slots x 40] + guard
  short* sM = (short*)(smem + 18080);        // [32][36] bf16

  const int tid = threadIdx.x;
  int w0, b, h, lin;
  tile_map(w0, b, h, lin);

  const int lane = tid & 63, lm = lane & 15, lq = lane >> 4;
  const int n = tid >> 6;  // wave == head in phase A
  const int idx16 = (lane ^ 16) << 2;        // bpermute byte indices
  const int idx32 = (lane ^ 32) << 2;

  const float hb2n = hb2[n];

  {  // zero-fill whole LDS (tap pads must be 0.0bf16, never garbage)
    int4* p = (int4*)smem;
    int4 z; z.x = z.y = z.z = z.w = 0;
    for (int e = tid; e < 20384 / 16; e += 256) p[e] = z;
  }
  __syncthreads();

  // stage x tile as bf16; channel stride 280 shorts; row r -> slot
  // {0,2,4,6,1,3,5} (slot stride 40 shorts) for conflict-free gathers
#pragma unroll 1
  for (int r = 0; r < 7; ++r) {
    int hr = h - 3 + r; hr = hr < 0 ? 0 : (hr > 127 ? 127 : hr);
    const int slot = (r < 4) ? (2 * r) : (2 * r - 7);
    const float* __restrict__ xrow = x + (size_t)((b * 128 + hr) * 256) * 34;
    short* __restrict__ sxr = sX + slot * 40;
    for (int e = tid; e < 39 * 16; e += 256) {
      const int c2 = e & 15;
      const int wp = e >> 4;
      const int wr = (w0 - 3 + wp) & 255;
      const float2 v = *(const float2*)&xrow[wr * 34 + c2 * 2];
      short* dp = sxr + (c2 * 2) * 280 + wp;
      dp[0]   = f2bf_fast(v.x);
      dp[280] = f2bf_fast(v.y);
    }
  }
  __syncthreads();

  const int* tpB = (const int*)sX;

  // ---- phase A: A=weights(rows=o), B=taps(cols=pixel) -> D[o, pixel]
#pragma unroll 1
  for (int par = 0; par < 2; ++par) {
    bfrag cw[2][2];
#pragma unroll
    for (int kt = 0; kt < 2; ++kt)
#pragma unroll
      for (int nt = 0; nt < 2; ++nt)
        cw[kt][nt] = *(const bfrag*)(wcb + h * 16384 + n * 4096 +
                         ((par * 2 + kt) * 2 + nt) * 512 + lane * 8);
    // per-lane bias/scale for this lane's 8 o-rows (o = lq*4+rr, +16)
    const float4 b0v = *(const float4*)(hb1e + n * 32 + lq * 4);
    const float4 b1v = *(const float4*)(hb1e + n * 32 + 16 + lq * 4);
    const float4 w0v = *(const float4*)(hw2 + n * 32 + lq * 4);
    const float4 w1v = *(const float4*)(hw2 + n * 32 + 16 + lq * 4);

#pragma unroll 1
    for (int i = 0; i < 8; ++i) {
      const int c = n * 8 + i;

      // tap B-frags: lane lm = pixel; u0 rows 0-3 (slots 2lq),
      // u1 rows 4-7 (slots 2lq+1)
      const int base0 = c * 140 + lq * 40 + lm;
      bfi4 u0, u1;
      u0.i.x = tpB[base0];      u0.i.y = tpB[base0 + 1];
      u0.i.z = tpB[base0 + 2];  u0.i.w = tpB[base0 + 3];
      u1.i.x = tpB[base0 + 20]; u1.i.y = tpB[base0 + 21];
      u1.i.z = tpB[base0 + 22]; u1.i.w = tpB[base0 + 23];

      ffrag h0 = {0.f, 0.f, 0.f, 0.f}, h1 = {0.f, 0.f, 0.f, 0.f};
      h0 = __builtin_amdgcn_mfma_f32_16x16x32_bf16(cw[0][0], u0.b, h0, 0, 0, 0);
      h0 = __builtin_amdgcn_mfma_f32_16x16x32_bf16(cw[1][0], u1.b, h0, 0, 0, 0);
      h1 = __builtin_amdgcn_mfma_f32_16x16x32_bf16(cw[0][1], u0.b, h1, 0, 0, 0);
      h1 = __builtin_amdgcn_mfma_f32_16x16x32_bf16(cw[1][1], u1.b, h1, 0, 0, 0);

      // in-lane o-contraction (two 4-deep chains), then 4-way lq reduce
      float s0 = gelu_f(h0[0] + b0v.x) * w0v.x;
      s0 += gelu_f(h0[1] + b0v.y) * w0v.y;
      s0 += gelu_f(h0[2] + b0v.z) * w0v.z;
      s0 += gelu_f(h0[3] + b0v.w) * w0v.w;
      float s1 = gelu_f(h1[0] + b1v.x) * w1v.x;
      s1 += gelu_f(h1[1] + b1v.y) * w1v.y;
      s1 += gelu_f(h1[2] + b1v.z) * w1v.z;
      s1 += gelu_f(h1[3] + b1v.w) * w1v.w;
      union { float f; int i; } sv, t1, t2;
      sv.f = s0 + s1;
      t1.i = __builtin_amdgcn_ds_bpermute(idx16, sv.i);
      sv.f += t1.f;
      t2.i = __builtin_amdgcn_ds_bpermute(idx32, sv.i);
      const float tot = sv.f + t2.f;

      const int p = 2 * lm + par;
      const float res = bf2f(sX[c * 280 + 243 + p]);  // center tap (slot 6)
      if (lq == 0) sM[p * 36 + c] = f2bf_fast(tot + hb2n + res);
    }
  }
  __syncthreads();

  // ---- phase B: fused MLP 32->512(gelu)->256(gelu)->32 (+residual)
  short* sT1h = (short*)smem;
  short* sT2  = (short*)smem;
  float* sO   = (float*)smem;
  const int wave = n;
  const int koff = lq * 8;
  const int mt3 = wave & 1;
  const int nt3 = wave >> 1;
  const int col3 = nt3 * 16 + lm;
  const int pixg = (b * 128 + h) * 256 + w0;
  const int n0 = wave * 4;

  ffrag acc[2][4];
#pragma unroll
  for (int mt = 0; mt < 2; ++mt)
#pragma unroll
    for (int ni = 0; ni < 4; ++ni) acc[mt][ni] = ffrag{0.f, 0.f, 0.f, 0.f};
  const short* w2base = fw2s + n0 * 512 + lane * 8;

#pragma unroll 1
  for (int H = 0; H < 2; ++H) {
    // layer 1, half H: A=fw1 frag (rows=ff1 cols), B=sM (cols=pixels)
#pragma unroll
    for (int ni = 0; ni < 4; ++ni) {
      const bfrag b1f = *(const bfrag*)(fw1s +
                          (H * 16 + wave * 4 + ni) * 512 + lane * 8);
      const int ntl = wave * 4 + ni;
      const float4 fb1v = *(const float4*)(fb1 + H * 256 + ntl * 16 + lq * 4);
#pragma unroll
      for (int mt = 0; mt < 2; ++mt) {
        const bfrag aFm = *(const bfrag*)(sM + (mt * 16 + lm) * 36 + koff);
        ffrag cc = {0.f, 0.f, 0.f, 0.f};
        cc = __builtin_amdgcn_mfma_f32_16x16x32_bf16(b1f, aFm, cc, 0, 0, 0);
        // D rows = 4 consecutive ff1 cols, col = pixel mt*16+lm -> b64 store
        int2 wv;
        wv.x = pkbf(gelu_f(cc[0] + fb1v.x), gelu_f(cc[1] + fb1v.y));
        wv.y = pkbf(gelu_f(cc[2] + fb1v.z), gelu_f(cc[3] + fb1v.w));
        *(int2*)(sT1h + (mt * 16 + lm) * 264 + ntl * 16 + lq * 4) = wv;
      }
    }
    __syncthreads();

    // layer 2: A=fw2 frag (rows=ff2 cols), B=sT1h (cols=pixels)
#pragma unroll 1
    for (int kt = 0; kt < 8; ++kt) {
      const bfrag a0 = *(const bfrag*)(sT1h + lm * 264 + kt * 32 + koff);
      const bfrag a1 = *(const bfrag*)(sT1h + (16 + lm) * 264 + kt * 32 + koff);
#pragma unroll
      for (int np = 0; np < 2; ++np) {
        const bfrag bv0 = *(const bfrag*)(w2base + (H * 8 + kt) * 8192 + (2 * np) * 512);
        const bfrag bv1 = *(const bfrag*)(w2base + (H * 8 + kt) * 8192 + (2 * np + 1) * 512);
        acc[0][2 * np]     = __builtin_amdgcn_mfma_f32_16x16x32_bf16(bv0, a0, acc[0][2 * np], 0, 0, 0);
        acc[1][2 * np]     = __builtin_amdgcn_mfma_f32_16x16x32_bf16(bv0, a1, acc[1][2 * np], 0, 0, 0);
        acc[0][2 * np + 1] = __builtin_amdgcn_mfma_f32_16x16x32_bf16(bv1, a0, acc[0][2 * np + 1], 0, 0, 0);
        acc[1][2 * np + 1] = __builtin_amdgcn_mfma_f32_16x16x32_bf16(bv1, a1, acc[1][2 * np + 1], 0, 0, 0);
      }
    }
    __syncthreads();   // before next half overwrites sT1h
  }

  // t2 epilogue: acc rows = 4 consecutive ff2 cols, col = pixel -> b64 store
#pragma unroll
  for (int mt = 0; mt < 2; ++mt)
#pragma unroll
    for (int ni = 0; ni < 4; ++ni) {
      const float4 fb2v = *(const float4*)(fb2 + (n0 + ni) * 16 + lq * 4);
      int2 wv;
      wv.x = pkbf(gelu_f(acc[mt][ni][0] + fb2v.x), gelu_f(acc[mt][ni][1] + fb2v.y));
      wv.y = pkbf(gelu_f(acc[mt][ni][2] + fb2v.z), gelu_f(acc[mt][ni][3] + fb2v.w));
      *(int2*)(sT2 + (mt * 16 + lm) * 264 + (n0 + ni) * 16 + lq * 4) = wv;
    }
  __syncthreads();

  // layer 3 (reads sT2; D rows = pixels as before)
  ffrag c3 = {0.f, 0.f, 0.f, 0.f};
  const short* sA3 = sT2 + (mt3 * 16 + lm) * 264 + koff;
#pragma unroll
  for (int kt = 0; kt < 8; ++kt) {
    const bfrag a = *(const bfrag*)(sA3 + kt * 32);
    const bfrag bw = *(const bfrag*)(fw3s + nt3 * 512 + kt * 1024 + lane * 8);
    c3 = __builtin_amdgcn_mfma_f32_16x16x32_bf16(a, bw, c3, 0, 0, 0);
  }
  __syncthreads();   // all sT2 reads done before sO overwrite
  {
    const float bias = fb3[col3];
#pragma unroll
    for (int r = 0; r < 4; ++r) {
      const int row = mt3 * 16 + lq * 4 + r;
      const float res = bf2f(sM[row * 36 + col3]);
      sO[row * 34 + col3] = c3[r] + bias + res;
    }
  }
  if (tid < 32) {   // sincos passthrough (x row L2-hot)
    const float2 scv =
        *(const float2*)&x[(size_t)(((b * 128 + h) * 256 + w0 + tid)) * 34 + 32];
    sO[tid * 34 + 32] = scv.x;
    sO[tid * 34 + 33] = scv.y;
  }
  __syncthreads();
  {
    const float4* sp = (const float4*)sO;           // 1088 floats = 272 f4
    float4* dp = (float4*)(outb + (size_t)pixg * 34);
    for (int e = tid; e < 272; e += 256) dp[e] = sp[e];
  }
}

// ---------------------------------------------------------------------------
extern "C" void kernel_launch(void* const* d_in, const int* in_sizes, int n_in,
                              void* d_out, int out_size, void* d_ws, size_t ws_size,
                              hipStream_t stream) {
  const float* x   = (const float*)d_in[0];
  const float* psi = (const float*)d_in[1];
  const float* dw  = (const float*)d_in[2];
  const float* db  = (const float*)d_in[3];
  const float* hw1 = (const float*)d_in[4];
  const float* hb1 = (const float*)d_in[5];
  const float* hw2 = (const float*)d_in[6];
  const float* hb2 = (const float*)d_in[7];
  const float* fw1 = (const float*)d_in[8];
  const float* fb1 = (const float*)d_in[9];
  const float* fw2 = (const float*)d_in[10];
  const float* fb2 = (const float*)d_in[11];
  const float* fw3 = (const float*)d_in[12];
  const float* fb3 = (const float*)d_in[13];
  float* outb = (float*)d_out;

  // workspace (~4.5 MB)
  short* wcb  = (short*)d_ws;        // 128*16384 = 2097152 shorts
  short* fw1s = wcb + 2097152;       // 16384
  short* fw2s = fw1s + 16384;        // 131072
  short* fw3s = fw2s + 131072;       // 8192
  float* hb1e = (float*)(fw3s + 8192);  // 128 floats

  hipLaunchKernelGGL(k01_prep, dim3(532), dim3(256), 0, stream,
                     psi, dw, db, fw1, fw2, fw3, hw1, hb1,
                     wcb, fw1s, fw2s, fw3s, hb1e);
  hipLaunchKernelGGL(k23_fused, dim3(8, 128, 2), dim3(256), 0, stream,
                     x, wcb, hb1e, hw2, hb2,
                     fw1s, fw2s, fw3s, fb1, fb2, fb3, outb);
}